// Round 6
// baseline (399.015 us; speedup 1.0000x reference)
//
#include <hip/hip_runtime.h>
#include <cstdint>
#include <cstddef>

#define NN 20000

typedef __bf16 bf16_t;
typedef __bf16 bf16x8 __attribute__((ext_vector_type(8)));
typedef __bf16 bf16x4 __attribute__((ext_vector_type(4)));
typedef float f32x4 __attribute__((ext_vector_type(4)));

#define AS1 __attribute__((address_space(1)))
#define AS3 __attribute__((address_space(3)))

__device__ __forceinline__ float lrelu(float x) { return x >= 0.f ? x : 0.2f * x; }
__device__ __forceinline__ float bflo(uint32_t u) { return __uint_as_float(u << 16); }
__device__ __forceinline__ float bfhi(uint32_t u) { return __uint_as_float(u & 0xffff0000u); }

__device__ __forceinline__ uint32_t pack2bf(float a, float b) {
  bf16_t x = (bf16_t)a, y = (bf16_t)b;
  uint16_t ux = __builtin_bit_cast(uint16_t, x);
  uint16_t uy = __builtin_bit_cast(uint16_t, y);
  return (uint32_t)ux | ((uint32_t)uy << 16);
}

// ---------------- CSR build (counting sort by dst) ----------------

__global__ void hist_kernel(const int* __restrict__ ei, int E, int N, int* __restrict__ cnt) {
  int i = blockIdx.x * 256 + threadIdx.x;
  if (i < E + N) {
    int dst = (i < E) ? ei[E + i] : (i - E);
    atomicAdd(&cnt[dst], 1);
  }
}

__global__ __launch_bounds__(1024) void scan_kernel(const int* __restrict__ cnt,
                                                    int* __restrict__ row_ptr,
                                                    int* __restrict__ cursor, int n) {
  __shared__ int wsum[16];
  const int t = threadIdx.x;
  const int lane = t & 63, w = t >> 6;
  int carry = 0;
  for (int base = 0; base < n; base += 1024) {
    int i = base + t;
    int v = (i < n) ? cnt[i] : 0;
    int x = v;
#pragma unroll
    for (int d = 1; d < 64; d <<= 1) {
      int y = __shfl_up(x, d);
      if (lane >= d) x += y;
    }
    if (lane == 63) wsum[w] = x;
    __syncthreads();
    if (t < 16) {
      int s = wsum[t];
#pragma unroll
      for (int d = 1; d < 16; d <<= 1) {
        int y = __shfl_up(s, d);
        if (t >= d) s += y;
      }
      wsum[t] = s;
    }
    __syncthreads();
    int blocksum = wsum[15];
    int wprefix = (w == 0) ? 0 : wsum[w - 1];
    int excl = carry + wprefix + (x - v);
    if (i < n) { row_ptr[i] = excl; cursor[i] = excl; }
    carry += blocksum;
    __syncthreads();
  }
  if (t == 0) row_ptr[n] = carry;
}

__global__ void scatter_kernel(const int* __restrict__ ei, int E, int N,
                               int* __restrict__ cursor, int* __restrict__ col) {
  int i = blockIdx.x * 256 + threadIdx.x;
  if (i < E + N) {
    int src, dst;
    if (i < E) { src = ei[i]; dst = ei[E + i]; }
    else       { src = i - E; dst = src; }
    int slot = atomicAdd(&cursor[dst], 1);
    col[slot] = src;
  }
}

// ---------------- dtype / weight prep ----------------

__global__ void cast_bf16_kernel(const float* __restrict__ in, bf16_t* __restrict__ out, int n4) {
  int i = blockIdx.x * 256 + threadIdx.x;
  if (i < n4) {
    float4 v = ((const float4*)in)[i];
    bf16x4 o;
    o.x = (bf16_t)v.x; o.y = (bf16_t)v.y; o.z = (bf16_t)v.z; o.w = (bf16_t)v.w;
    ((bf16x4*)out)[i] = o;
  }
}

// Merged weight prep: W [K, H*Cw] fp32 -> Bt [Cw, H*K] bf16,
// Bt[c, h*K+k] = scale * W[k, h*Cw+c]
struct WDesc { const float* W; bf16_t* Bt; int K; int Cw; int H; float scale; int b0; };
struct WPack { WDesc d[4]; };

__global__ void wprep(WPack p) {
  __shared__ float tile[32][33];
  int i = 3;
#pragma unroll
  for (int k = 2; k >= 0; --k)
    if ((int)blockIdx.x < p.d[k + 1].b0) i = k;
  const WDesc de = p.d[i];
  const int bi = blockIdx.x - de.b0;
  const int ktiles = de.K / 32;
  const int kt = bi % ktiles, rt = bi / ktiles;
  const int gc = rt * 32;
  const int h = gc / de.Cw, c0 = gc % de.Cw;
  const int tx = threadIdx.x, ty = threadIdx.y;
#pragma unroll
  for (int r = 0; r < 32; r += 8)
    tile[ty + r][tx] = de.W[(size_t)(kt * 32 + ty + r) * (de.H * de.Cw) + h * de.Cw + c0 + tx];
  __syncthreads();
#pragma unroll
  for (int r = 0; r < 32; r += 8)
    de.Bt[(size_t)(c0 + ty + r) * (de.H * de.K) + h * de.K + kt * 32 + tx] =
        (bf16_t)(de.scale * tile[tx][ty + r]);
}

// Merged alpha projections: P[j*K + k] = sum_c W[k, h*128+c] * a_j[h*128+c]
__global__ __launch_bounds__(128) void alpha_proj_all(
    const float* __restrict__ W1, const float* __restrict__ as1, const float* __restrict__ ad1,
    const float* __restrict__ W2, const float* __restrict__ as2, const float* __restrict__ ad2,
    const float* __restrict__ W3, const float* __restrict__ as3, const float* __restrict__ ad3,
    float* __restrict__ P1, float* __restrict__ P2, float* __restrict__ P3) {
  const float *W, *asrc, *adst;
  float* P;
  int K, H, k;
  const int b = blockIdx.x;
  if (b < 256)      { W = W1; asrc = as1; adst = ad1; P = P1; K = 256; H = 4; k = b; }
  else if (b < 384) { W = W2; asrc = as2; adst = ad2; P = P2; K = 128; H = 4; k = b - 256; }
  else              { W = W3; asrc = as3; adst = ad3; P = P3; K = 128; H = 1; k = b - 384; }
  __shared__ float red[2];
  const int c = threadIdx.x;
  for (int j = 0; j < 2 * H; ++j) {
    const int h = (j < H) ? j : j - H;
    const float* a = (j < H) ? asrc : adst;
    float pv = W[(size_t)k * (H * 128) + h * 128 + c] * a[h * 128 + c];
#pragma unroll
    for (int d = 1; d < 64; d <<= 1) pv += __shfl_xor(pv, d);
    if ((c & 63) == 0) red[c >> 6] = pv;
    __syncthreads();
    if (c == 0) P[j * K + k] = red[0] + red[1];
    __syncthreads();
  }
}

// M3t[c*128+k] = (bf16)(W3 @ L1)[k,c];  bm[c] = b3 @ L1[:,c] + l1b[c]
__global__ __launch_bounds__(256) void merge_w3l1(const float* __restrict__ W3,
                                                  const float* __restrict__ L1,
                                                  const float* __restrict__ b3,
                                                  const float* __restrict__ l1b,
                                                  bf16_t* __restrict__ M3t,
                                                  float* __restrict__ bm) {
  const int idx = blockIdx.x * 256 + threadIdx.x;
  const int k = idx >> 7, c = idx & 127;
  float s = 0.f;
  for (int m = 0; m < 128; ++m) s += W3[k * 128 + m] * L1[m * 128 + c];
  M3t[c * 128 + k] = (bf16_t)s;
  if (k == 0) {
    float t = l1b[c];
    for (int m = 0; m < 128; ++m) t += b3[m] * L1[m * 128 + c];
    bm[c] = t;
  }
}

// ---------------- bf16 MFMA GEMM: C = act(A @ Bt^T + bias) ----------------
// ACT: 0=none, 1=relu, 2=sigmoid, 3=BN(eval)+relu

template <int TN, int ACT, typename OUT_T>
__global__ __launch_bounds__(256) void gemm_mfma(const bf16_t* __restrict__ A,
                                                 const bf16_t* __restrict__ Bt,
                                                 const float* __restrict__ bias,
                                                 const float* __restrict__ bng,
                                                 const float* __restrict__ bnb,
                                                 const float* __restrict__ bnm,
                                                 const float* __restrict__ bnv,
                                                 OUT_T* __restrict__ C,
                                                 int M, int N, int K) {
  constexpr int TM = 128, BK = 64;
  constexpr int MT = (TN == 128) ? 4 : 2;
  constexpr int NRB = (TN * BK * 2) / 4096;
  __shared__ __align__(16) bf16_t As[TM * BK];
  __shared__ __align__(16) bf16_t Bs[TN * BK];

  const int t = threadIdx.x;
  const int wave = t >> 6, lane = t & 63;
  const int ln15 = lane & 15, quad = lane >> 4;
  const int bm = blockIdx.x * TM;
  const int bn = blockIdx.y * TN;
  const int wm = (TN == 128) ? (wave >> 1) * 64 : wave * 32;
  const int wn = (TN == 128) ? (wave & 1) * 64 : 0;
  const int rowLimA = M - 1 - bm;
  const size_t strideAB = (size_t)K * 2;

  f32x4 acc[MT][4];
#pragma unroll
  for (int mi = 0; mi < MT; ++mi)
#pragma unroll
    for (int ni = 0; ni < 4; ++ni) acc[mi][ni] = (f32x4){0.f, 0.f, 0.f, 0.f};

  const char* gA = (const char*)(A + (size_t)bm * K);
  const char* gB = (const char*)(Bt + (size_t)bn * K);

  for (int k0 = 0; k0 < K; k0 += BK) {
#pragma unroll
    for (int r = 0; r < 4; ++r) {
      int base = (wave * 4 + r) * 1024;
      int flat = base + lane * 16;
      int row = flat >> 7;
      int grow = row < rowLimA ? row : rowLimA;
      const char* gp = gA + (size_t)grow * strideAB + (size_t)(k0 * 2) + (flat & 127);
      __builtin_amdgcn_global_load_lds((const AS1 void*)gp,
                                       (AS3 void*)((char*)As + base), 16, 0, 0);
    }
#pragma unroll
    for (int r = 0; r < NRB; ++r) {
      int base = (wave * NRB + r) * 1024;
      int flat = base + lane * 16;
      int row = flat >> 7;
      const char* gp = gB + (size_t)row * strideAB + (size_t)(k0 * 2) + (flat & 127);
      __builtin_amdgcn_global_load_lds((const AS1 void*)gp,
                                       (AS3 void*)((char*)Bs + base), 16, 0, 0);
    }
    __syncthreads();
#pragma unroll
    for (int kk = 0; kk < BK; kk += 32) {
      bf16x8 af[MT], bfr[4];
#pragma unroll
      for (int mi = 0; mi < MT; ++mi)
        af[mi] = *(const bf16x8*)&As[(wm + mi * 16 + ln15) * BK + kk + quad * 8];
#pragma unroll
      for (int ni = 0; ni < 4; ++ni)
        bfr[ni] = *(const bf16x8*)&Bs[(wn + ni * 16 + ln15) * BK + kk + quad * 8];
#pragma unroll
      for (int mi = 0; mi < MT; ++mi)
#pragma unroll
        for (int ni = 0; ni < 4; ++ni)
          acc[mi][ni] = __builtin_amdgcn_mfma_f32_16x16x32_bf16(af[mi], bfr[ni], acc[mi][ni], 0, 0, 0);
    }
    __syncthreads();
  }

#pragma unroll
  for (int mi = 0; mi < MT; ++mi) {
    int r0 = bm + wm + mi * 16 + quad * 4;
#pragma unroll
    for (int ni = 0; ni < 4; ++ni) {
      int c = bn + wn + ni * 16 + ln15;
      float bv = bias ? bias[c] : 0.f;
      float sc = 1.f, sh = 0.f;
      if (ACT == 3) {
        sc = bng[c] * rsqrtf(bnv[c] + 1e-5f);
        sh = bnb[c] - bnm[c] * sc;
      }
#pragma unroll
      for (int reg = 0; reg < 4; ++reg) {
        int r = r0 + reg;
        if (r < M) {
          float v = acc[mi][ni][reg] + bv;
          if (ACT == 1) v = fmaxf(v, 0.f);
          else if (ACT == 2) v = 1.f / (1.f + __expf(-v));
          else if (ACT == 3) v = fmaxf(v * sc + sh, 0.f);
          C[(size_t)r * N + c] = (OUT_T)v;
        }
      }
    }
  }
}

// ---------------- alpha logits: asad[n, j] = f[n,:] . P[j,:]  (j < 2H) ----------------

template <int K, int H>
__global__ __launch_bounds__(256) void alpha_gemm(const bf16_t* __restrict__ f,
                                                  const float* __restrict__ P,
                                                  float* __restrict__ asad) {
  constexpr int J = 2 * H;
  constexpr int KC = K / 64;
  const int wv = threadIdx.x >> 6, lane = threadIdx.x & 63;
  const int n = blockIdx.x * 4 + wv;
  float v[KC];
  if (KC == 4) {
    uint2 pv = *(const uint2*)&f[(size_t)n * K + lane * 4];
    v[0] = bflo(pv.x); v[1] = bfhi(pv.x); v[2] = bflo(pv.y); v[3] = bfhi(pv.y);
  } else {
    uint32_t pv = *(const uint32_t*)&f[(size_t)n * K + lane * 2];
    v[0] = bflo(pv); v[1] = bfhi(pv);
  }
  float s[J];
#pragma unroll
  for (int j = 0; j < J; ++j) {
    float acc = 0.f;
#pragma unroll
    for (int q = 0; q < KC; ++q) acc += v[q] * P[j * K + lane * KC + q];
    s[j] = acc;
  }
#pragma unroll
  for (int j = 0; j < J; ++j)
#pragma unroll
    for (int d = 1; d < 64; d <<= 1) s[j] += __shfl_xor(s[j], d);
  if (lane == 0) {
#pragma unroll
    for (int j = 0; j < J; ++j) asad[(size_t)n * J + j] = s[j];
  }
}

// ---------------- per-edge alpha precompute ----------------

__global__ __launch_bounds__(256) void edge_alpha4(const float* __restrict__ asad,
                                                   const int* __restrict__ rp,
                                                   const int* __restrict__ cs,
                                                   float4* __restrict__ aw) {
  const int wv = threadIdx.x >> 6, lane = threadIdx.x & 63;
  const int n = blockIdx.x * 4 + wv;
  const int r0 = rp[n], r1 = rp[n + 1];
  const int deg = r1 - r0;
  const float4 adv = *(const float4*)&asad[(size_t)n * 8 + 4];

  if (deg <= 64) {
    const bool valid = lane < deg;
    const int s = cs[r0 + (valid ? lane : 0)];
    const float4 av = *(const float4*)&asad[(size_t)s * 8];
    float e0 = valid ? lrelu(av.x + adv.x) : -1e30f;
    float e1 = valid ? lrelu(av.y + adv.y) : -1e30f;
    float e2 = valid ? lrelu(av.z + adv.z) : -1e30f;
    float e3 = valid ? lrelu(av.w + adv.w) : -1e30f;
    float m0 = e0, m1 = e1, m2 = e2, m3 = e3;
#pragma unroll
    for (int d = 1; d < 64; d <<= 1) {
      m0 = fmaxf(m0, __shfl_xor(m0, d)); m1 = fmaxf(m1, __shfl_xor(m1, d));
      m2 = fmaxf(m2, __shfl_xor(m2, d)); m3 = fmaxf(m3, __shfl_xor(m3, d));
    }
    float x0 = valid ? __expf(e0 - m0) : 0.f;
    float x1 = valid ? __expf(e1 - m1) : 0.f;
    float x2 = valid ? __expf(e2 - m2) : 0.f;
    float x3 = valid ? __expf(e3 - m3) : 0.f;
    float d0 = x0, d1 = x1, d2 = x2, d3 = x3;
#pragma unroll
    for (int d = 1; d < 64; d <<= 1) {
      d0 += __shfl_xor(d0, d); d1 += __shfl_xor(d1, d);
      d2 += __shfl_xor(d2, d); d3 += __shfl_xor(d3, d);
    }
    if (valid)
      aw[r0 + lane] = make_float4(x0 / (d0 + 1e-16f), x1 / (d1 + 1e-16f),
                                  x2 / (d2 + 1e-16f), x3 / (d3 + 1e-16f));
  } else {
    float m0 = -1e30f, m1 = -1e30f, m2 = -1e30f, m3 = -1e30f;
    for (int i = r0 + lane; i < r1; i += 64) {
      const float4 av = *(const float4*)&asad[(size_t)cs[i] * 8];
      m0 = fmaxf(m0, lrelu(av.x + adv.x)); m1 = fmaxf(m1, lrelu(av.y + adv.y));
      m2 = fmaxf(m2, lrelu(av.z + adv.z)); m3 = fmaxf(m3, lrelu(av.w + adv.w));
    }
#pragma unroll
    for (int d = 1; d < 64; d <<= 1) {
      m0 = fmaxf(m0, __shfl_xor(m0, d)); m1 = fmaxf(m1, __shfl_xor(m1, d));
      m2 = fmaxf(m2, __shfl_xor(m2, d)); m3 = fmaxf(m3, __shfl_xor(m3, d));
    }
    float d0 = 0.f, d1 = 0.f, d2 = 0.f, d3 = 0.f;
    for (int i = r0 + lane; i < r1; i += 64) {
      const float4 av = *(const float4*)&asad[(size_t)cs[i] * 8];
      d0 += __expf(lrelu(av.x + adv.x) - m0); d1 += __expf(lrelu(av.y + adv.y) - m1);
      d2 += __expf(lrelu(av.z + adv.z) - m2); d3 += __expf(lrelu(av.w + adv.w) - m3);
    }
#pragma unroll
    for (int d = 1; d < 64; d <<= 1) {
      d0 += __shfl_xor(d0, d); d1 += __shfl_xor(d1, d);
      d2 += __shfl_xor(d2, d); d3 += __shfl_xor(d3, d);
    }
    const float i0 = 1.f / (d0 + 1e-16f), i1 = 1.f / (d1 + 1e-16f);
    const float i2 = 1.f / (d2 + 1e-16f), i3 = 1.f / (d3 + 1e-16f);
    for (int i = r0 + lane; i < r1; i += 64) {
      const float4 av = *(const float4*)&asad[(size_t)cs[i] * 8];
      aw[i] = make_float4(__expf(lrelu(av.x + adv.x) - m0) * i0,
                          __expf(lrelu(av.y + adv.y) - m1) * i1,
                          __expf(lrelu(av.z + adv.z) - m2) * i2,
                          __expf(lrelu(av.w + adv.w) - m3) * i3);
    }
  }
}

__global__ __launch_bounds__(256) void edge_alpha1(const float* __restrict__ asad,
                                                   const int* __restrict__ rp,
                                                   const int* __restrict__ cs,
                                                   float* __restrict__ aw) {
  const int wv = threadIdx.x >> 6, lane = threadIdx.x & 63;
  const int n = blockIdx.x * 4 + wv;
  const int r0 = rp[n], r1 = rp[n + 1];
  const int deg = r1 - r0;
  const float adv = asad[(size_t)n * 2 + 1];

  if (deg <= 64) {
    const bool valid = lane < deg;
    const int s = cs[r0 + (valid ? lane : 0)];
    float e = valid ? lrelu(asad[(size_t)s * 2] + adv) : -1e30f;
    float m = e;
#pragma unroll
    for (int d = 1; d < 64; d <<= 1) m = fmaxf(m, __shfl_xor(m, d));
    float x = valid ? __expf(e - m) : 0.f;
    float den = x;
#pragma unroll
    for (int d = 1; d < 64; d <<= 1) den += __shfl_xor(den, d);
    if (valid) aw[r0 + lane] = x / (den + 1e-16f);
  } else {
    float m = -1e30f;
    for (int i = r0 + lane; i < r1; i += 64) m = fmaxf(m, lrelu(asad[(size_t)cs[i] * 2] + adv));
#pragma unroll
    for (int d = 1; d < 64; d <<= 1) m = fmaxf(m, __shfl_xor(m, d));
    float den = 0.f;
    for (int i = r0 + lane; i < r1; i += 64) den += __expf(lrelu(asad[(size_t)cs[i] * 2] + adv) - m);
#pragma unroll
    for (int d = 1; d < 64; d <<= 1) den += __shfl_xor(den, d);
    const float dinv = 1.f / (den + 1e-16f);
    for (int i = r0 + lane; i < r1; i += 64)
      aw[i] = __expf(lrelu(asad[(size_t)cs[i] * 2] + adv) - m) * dinv;
  }
}

// ---------------- chunked gather: agg[n, h*K + c] = sum_e aw[e][h] * f[src_e, c] ------
// Block = 256 threads = 8 nodes x 32 lanes. Chunk = 64 feats (128 B).
// chunk = blockIdx.x % C so each XCD's blocks touch one 2.56 MB slice of f.

template <int K>
__global__ __launch_bounds__(256) void gat_gather4(const bf16_t* __restrict__ f,
                                                   const float4* __restrict__ aw,
                                                   const int* __restrict__ rp,
                                                   const int* __restrict__ cs,
                                                   bf16_t* __restrict__ agg) {
  constexpr int C = K / 64;
  const int chunk = blockIdx.x % C;
  const int ngrp = blockIdx.x / C;
  const int grp = threadIdx.x >> 5, tl = threadIdx.x & 31;
  const int n = ngrp * 8 + grp;
  const int boff = chunk * 128 + tl * 4;  // byte offset within f row
  const int r0 = rp[n], r1 = rp[n + 1];
  const char* fb = (const char*)f;
  const size_t rowb = (size_t)K * 2;

  float a00 = 0.f, a01 = 0.f, a10 = 0.f, a11 = 0.f;
  float a20 = 0.f, a21 = 0.f, a30 = 0.f, a31 = 0.f;

  auto fmae = [&](uint32_t v, float4 a) {
    float f0 = bflo(v), f1 = bfhi(v);
    a00 += a.x * f0; a01 += a.x * f1;
    a10 += a.y * f0; a11 += a.y * f1;
    a20 += a.z * f0; a21 += a.z * f1;
    a30 += a.w * f0; a31 += a.w * f1;
  };

  int i = r0;
  for (; i + 4 <= r1; i += 4) {
    int s0 = cs[i], s1 = cs[i + 1], s2 = cs[i + 2], s3 = cs[i + 3];
    float4 w0 = aw[i], w1 = aw[i + 1], w2 = aw[i + 2], w3 = aw[i + 3];
    uint32_t v0 = *(const uint32_t*)(fb + (size_t)s0 * rowb + boff);
    uint32_t v1 = *(const uint32_t*)(fb + (size_t)s1 * rowb + boff);
    uint32_t v2 = *(const uint32_t*)(fb + (size_t)s2 * rowb + boff);
    uint32_t v3 = *(const uint32_t*)(fb + (size_t)s3 * rowb + boff);
    fmae(v0, w0); fmae(v1, w1); fmae(v2, w2); fmae(v3, w3);
  }
  for (; i < r1; ++i) {
    int s = cs[i];
    float4 w = aw[i];
    fmae(*(const uint32_t*)(fb + (size_t)s * rowb + boff), w);
  }

  const int col = chunk * 64 + tl * 2;
  bf16_t* op = agg + (size_t)n * (4 * K) + col;
  *(uint32_t*)(op + 0 * K) = pack2bf(a00, a01);
  *(uint32_t*)(op + 1 * K) = pack2bf(a10, a11);
  *(uint32_t*)(op + 2 * K) = pack2bf(a20, a21);
  *(uint32_t*)(op + 3 * K) = pack2bf(a30, a31);
}

template <int K>
__global__ __launch_bounds__(256) void gat_gather1(const bf16_t* __restrict__ f,
                                                   const float* __restrict__ aw,
                                                   const int* __restrict__ rp,
                                                   const int* __restrict__ cs,
                                                   bf16_t* __restrict__ agg) {
  constexpr int C = K / 64;
  const int chunk = blockIdx.x % C;
  const int ngrp = blockIdx.x / C;
  const int grp = threadIdx.x >> 5, tl = threadIdx.x & 31;
  const int n = ngrp * 8 + grp;
  const int boff = chunk * 128 + tl * 4;
  const int r0 = rp[n], r1 = rp[n + 1];
  const char* fb = (const char*)f;
  const size_t rowb = (size_t)K * 2;

  float a0 = 0.f, a1 = 0.f;
  int i = r0;
  for (; i + 4 <= r1; i += 4) {
    int s0 = cs[i], s1 = cs[i + 1], s2 = cs[i + 2], s3 = cs[i + 3];
    float w0 = aw[i], w1 = aw[i + 1], w2 = aw[i + 2], w3 = aw[i + 3];
    uint32_t v0 = *(const uint32_t*)(fb + (size_t)s0 * rowb + boff);
    uint32_t v1 = *(const uint32_t*)(fb + (size_t)s1 * rowb + boff);
    uint32_t v2 = *(const uint32_t*)(fb + (size_t)s2 * rowb + boff);
    uint32_t v3 = *(const uint32_t*)(fb + (size_t)s3 * rowb + boff);
    a0 += w0 * bflo(v0); a1 += w0 * bfhi(v0);
    a0 += w1 * bflo(v1); a1 += w1 * bfhi(v1);
    a0 += w2 * bflo(v2); a1 += w2 * bfhi(v2);
    a0 += w3 * bflo(v3); a1 += w3 * bfhi(v3);
  }
  for (; i < r1; ++i) {
    uint32_t v = *(const uint32_t*)(fb + (size_t)cs[i] * rowb + boff);
    a0 += aw[i] * bflo(v); a1 += aw[i] * bfhi(v);
  }

  const int col = chunk * 64 + tl * 2;
  *(uint32_t*)&agg[(size_t)n * K + col] = pack2bf(a0, a1);
}

// ---------------- launch ----------------

extern "C" void kernel_launch(void* const* d_in, const int* in_sizes, int n_in,
                              void* d_out, int out_size, void* d_ws, size_t ws_size,
                              hipStream_t stream) {
  const float* x      = (const float*)d_in[0];
  const int*   ei     = (const int*)d_in[1];
  const float* W1     = (const float*)d_in[2];
  const float* a_src1 = (const float*)d_in[3];
  const float* a_dst1 = (const float*)d_in[4];
  const float* b1     = (const float*)d_in[5];
  const float* W2     = (const float*)d_in[6];
  const float* a_src2 = (const float*)d_in[7];
  const float* a_dst2 = (const float*)d_in[8];
  const float* b2     = (const float*)d_in[9];
  const float* W3     = (const float*)d_in[10];
  const float* a_src3 = (const float*)d_in[11];
  const float* a_dst3 = (const float*)d_in[12];
  const float* b3     = (const float*)d_in[13];
  const float* bn1g = (const float*)d_in[14];
  const float* bn1b = (const float*)d_in[15];
  const float* bn1m = (const float*)d_in[16];
  const float* bn1v = (const float*)d_in[17];
  const float* bn2g = (const float*)d_in[18];
  const float* bn2b = (const float*)d_in[19];
  const float* bn2m = (const float*)d_in[20];
  const float* bn2v = (const float*)d_in[21];
  const float* l1w = (const float*)d_in[22];
  const float* l1b = (const float*)d_in[23];
  const float* l2w = (const float*)d_in[24];
  const float* l2b = (const float*)d_in[25];
  const float* l3w = (const float*)d_in[26];
  const float* l3b = (const float*)d_in[27];
  float* out = (float*)d_out;

  const int N = NN;
  const int E = in_sizes[1] / 2;
  const int ET = E + N;

  char* p = (char*)d_ws;
  auto carve = [&](size_t bytes) {
    char* q = p;
    p += (bytes + 255) & ~(size_t)255;
    return q;
  };
  bf16_t* xb    = (bf16_t*)carve((size_t)N * 256 * 2);   // 10.24 MB
  char*   aggr  = carve((size_t)N * 1024 * 2);           // 40.96 MB (aliased)
  bf16_t* f1b   = (bf16_t*)carve((size_t)N * 128 * 2);
  bf16_t* f2b   = (bf16_t*)carve((size_t)N * 128 * 2);
  float* asad   = (float*)carve((size_t)N * 8 * 4);
  float4* aw4   = (float4*)carve((size_t)ET * 16);
  float* aw1    = (float*)carve((size_t)ET * 4);
  int* cnt      = (int*)carve((size_t)N * 4);
  int* cursor   = (int*)carve((size_t)N * 4);
  int* row_ptr  = (int*)carve((size_t)(N + 1) * 4);
  int* col      = (int*)carve((size_t)ET * 4);
  bf16_t* Ws1t  = (bf16_t*)carve((size_t)128 * 1024 * 2);
  bf16_t* Ws2t  = (bf16_t*)carve((size_t)128 * 512 * 2);
  bf16_t* M3t   = (bf16_t*)carve((size_t)128 * 128 * 2);
  bf16_t* l2t   = (bf16_t*)carve((size_t)64 * 128 * 2);
  bf16_t* l3t   = (bf16_t*)carve((size_t)64 * 64 * 2);
  float* P1     = (float*)carve((size_t)8 * 256 * 4);
  float* P2     = (float*)carve((size_t)8 * 128 * 4);
  float* P3     = (float*)carve((size_t)2 * 128 * 4);
  float* bm     = (float*)carve((size_t)128 * 4);
  (void)ws_size; (void)n_in; (void)out_size;

  bf16_t* aggb = (bf16_t*)aggr;
  bf16_t* m1b  = (bf16_t*)(aggr + (8u << 20));
  bf16_t* m2b  = (bf16_t*)(aggr + (16u << 20));

  // --- CSR build ---
  hipMemsetAsync(cnt, 0, (size_t)N * 4, stream);
  int eb = (ET + 255) / 256;
  hist_kernel<<<eb, 256, 0, stream>>>(ei, E, N, cnt);
  scan_kernel<<<1, 1024, 0, stream>>>(cnt, row_ptr, cursor, N);
  scatter_kernel<<<eb, 256, 0, stream>>>(ei, E, N, cursor, col);

  // --- prep ---
  cast_bf16_kernel<<<(N * 256 / 4 + 255) / 256, 256, 0, stream>>>(x, xb, N * 256 / 4);
  WPack wp;
  wp.d[0] = {W1,  Ws1t, 256, 128, 4, 0.25f, 0};    // 128 tiles
  wp.d[1] = {W2,  Ws2t, 128, 128, 4, 0.25f, 128};  // 64 tiles
  wp.d[2] = {l2w, l2t,  128, 64,  1, 1.0f,  192};  // 8 tiles
  wp.d[3] = {l3w, l3t,  64,  64,  1, 1.0f,  200};  // 4 tiles -> 204
  wprep<<<204, dim3(32, 8), 0, stream>>>(wp);
  alpha_proj_all<<<512, 128, 0, stream>>>(W1, a_src1, a_dst1, W2, a_src2, a_dst2,
                                          W3, a_src3, a_dst3, P1, P2, P3);
  merge_w3l1<<<64, 256, 0, stream>>>(W3, l1w, b3, l1b, M3t, bm);

  const int gm = (N + 127) / 128;  // 157
  const int ab = N / 4;            // 5000
  const int gg = N / 8;            // 2500 node groups

  // --- GAT layer 1 ---
  alpha_gemm<256, 4><<<ab, 256, 0, stream>>>(xb, P1, asad);
  edge_alpha4<<<ab, 256, 0, stream>>>(asad, row_ptr, col, aw4);
  gat_gather4<256><<<gg * 4, 256, 0, stream>>>(xb, aw4, row_ptr, col, aggb);
  gemm_mfma<64, 3, bf16_t><<<dim3(gm, 2), 256, 0, stream>>>(
      aggb, Ws1t, b1, bn1g, bn1b, bn1m, bn1v, f1b, N, 128, 1024);

  // --- GAT layer 2 ---
  alpha_gemm<128, 4><<<ab, 256, 0, stream>>>(f1b, P2, asad);
  edge_alpha4<<<ab, 256, 0, stream>>>(asad, row_ptr, col, aw4);
  gat_gather4<128><<<gg * 2, 256, 0, stream>>>(f1b, aw4, row_ptr, col, aggb);
  gemm_mfma<64, 3, bf16_t><<<dim3(gm, 2), 256, 0, stream>>>(
      aggb, Ws2t, b2, bn2g, bn2b, bn2m, bn2v, f2b, N, 128, 512);

  // --- GAT layer 3 (H=1) fused with classifier l1 ---
  alpha_gemm<128, 1><<<ab, 256, 0, stream>>>(f2b, P3, asad);
  edge_alpha1<<<ab, 256, 0, stream>>>(asad, row_ptr, col, aw1);
  gat_gather1<128><<<gg * 2, 256, 0, stream>>>(f2b, aw1, row_ptr, col, aggb);
  gemm_mfma<64, 1, bf16_t><<<dim3(gm, 2), 256, 0, stream>>>(
      aggb, M3t, bm, nullptr, nullptr, nullptr, nullptr, m1b, N, 128, 128);

  // --- classifier tail ---
  gemm_mfma<64, 1, bf16_t><<<dim3(gm, 1), 256, 0, stream>>>(
      m1b, l2t, l2b, nullptr, nullptr, nullptr, nullptr, m2b, N, 64, 128);
  gemm_mfma<64, 2, float><<<dim3(gm, 1), 256, 0, stream>>>(
      m2b, l3t, l3b, nullptr, nullptr, nullptr, nullptr, out, N, 64, 64);
}

// Round 7
// 347.445 us; speedup vs baseline: 1.1484x; 1.1484x over previous
//
#include <hip/hip_runtime.h>
#include <cstdint>
#include <cstddef>

#define NN 20000

typedef __bf16 bf16_t;
typedef __bf16 bf16x8 __attribute__((ext_vector_type(8)));
typedef __bf16 bf16x4 __attribute__((ext_vector_type(4)));
typedef float f32x4 __attribute__((ext_vector_type(4)));

#define AS1 __attribute__((address_space(1)))
#define AS3 __attribute__((address_space(3)))

__device__ __forceinline__ float lrelu(float x) { return x >= 0.f ? x : 0.2f * x; }
__device__ __forceinline__ float bflo(uint32_t u) { return __uint_as_float(u << 16); }
__device__ __forceinline__ float bfhi(uint32_t u) { return __uint_as_float(u & 0xffff0000u); }

__device__ __forceinline__ uint32_t pack2bf(float a, float b) {
  bf16_t x = (bf16_t)a, y = (bf16_t)b;
  uint16_t ux = __builtin_bit_cast(uint16_t, x);
  uint16_t uy = __builtin_bit_cast(uint16_t, y);
  return (uint32_t)ux | ((uint32_t)uy << 16);
}

// ---------------- CSR build (counting sort by dst) ----------------

__global__ void hist_kernel(const int* __restrict__ ei, int E, int N, int* __restrict__ cnt) {
  int i = blockIdx.x * 256 + threadIdx.x;
  if (i < E + N) {
    int dst = (i < E) ? ei[E + i] : (i - E);
    atomicAdd(&cnt[dst], 1);
  }
}

__global__ __launch_bounds__(1024) void scan_kernel(const int* __restrict__ cnt,
                                                    int* __restrict__ row_ptr,
                                                    int* __restrict__ cursor, int n) {
  __shared__ int wsum[16];
  const int t = threadIdx.x;
  const int lane = t & 63, w = t >> 6;
  int carry = 0;
  for (int base = 0; base < n; base += 1024) {
    int i = base + t;
    int v = (i < n) ? cnt[i] : 0;
    int x = v;
#pragma unroll
    for (int d = 1; d < 64; d <<= 1) {
      int y = __shfl_up(x, d);
      if (lane >= d) x += y;
    }
    if (lane == 63) wsum[w] = x;
    __syncthreads();
    if (t < 16) {
      int s = wsum[t];
#pragma unroll
      for (int d = 1; d < 16; d <<= 1) {
        int y = __shfl_up(s, d);
        if (t >= d) s += y;
      }
      wsum[t] = s;
    }
    __syncthreads();
    int blocksum = wsum[15];
    int wprefix = (w == 0) ? 0 : wsum[w - 1];
    int excl = carry + wprefix + (x - v);
    if (i < n) { row_ptr[i] = excl; cursor[i] = excl; }
    carry += blocksum;
    __syncthreads();
  }
  if (t == 0) row_ptr[n] = carry;
}

__global__ void scatter_kernel(const int* __restrict__ ei, int E, int N,
                               int* __restrict__ cursor, int* __restrict__ col) {
  int i = blockIdx.x * 256 + threadIdx.x;
  if (i < E + N) {
    int src, dst;
    if (i < E) { src = ei[i]; dst = ei[E + i]; }
    else       { src = i - E; dst = src; }
    int slot = atomicAdd(&cursor[dst], 1);
    col[slot] = src;
  }
}

// ---------------- weight prep ----------------

// Merged weight prep: W [K, H*Cw] fp32 -> Bt [Cw, H*K] bf16,
// Bt[c, h*K+k] = scale * W[k, h*Cw+c]
struct WDesc { const float* W; bf16_t* Bt; int K; int Cw; int H; float scale; int b0; };
struct WPack { WDesc d[4]; };

__global__ void wprep(WPack p) {
  __shared__ float tile[32][33];
  int i = 3;
#pragma unroll
  for (int k = 2; k >= 0; --k)
    if ((int)blockIdx.x < p.d[k + 1].b0) i = k;
  const WDesc de = p.d[i];
  const int bi = blockIdx.x - de.b0;
  const int ktiles = de.K / 32;
  const int kt = bi % ktiles, rt = bi / ktiles;
  const int gc = rt * 32;
  const int h = gc / de.Cw, c0 = gc % de.Cw;
  const int tx = threadIdx.x, ty = threadIdx.y;
#pragma unroll
  for (int r = 0; r < 32; r += 8)
    tile[ty + r][tx] = de.W[(size_t)(kt * 32 + ty + r) * (de.H * de.Cw) + h * de.Cw + c0 + tx];
  __syncthreads();
#pragma unroll
  for (int r = 0; r < 32; r += 8)
    de.Bt[(size_t)(c0 + ty + r) * (de.H * de.K) + h * de.K + kt * 32 + tx] =
        (bf16_t)(de.scale * tile[tx][ty + r]);
}

// Merged alpha projections: P[j*K + k] = sum_c W[k, h*128+c] * a_j[h*128+c]
__global__ __launch_bounds__(128) void alpha_proj_all(
    const float* __restrict__ W1, const float* __restrict__ as1, const float* __restrict__ ad1,
    const float* __restrict__ W2, const float* __restrict__ as2, const float* __restrict__ ad2,
    const float* __restrict__ W3, const float* __restrict__ as3, const float* __restrict__ ad3,
    float* __restrict__ P1, float* __restrict__ P2, float* __restrict__ P3) {
  const float *W, *asrc, *adst;
  float* P;
  int K, H, k;
  const int b = blockIdx.x;
  if (b < 256)      { W = W1; asrc = as1; adst = ad1; P = P1; K = 256; H = 4; k = b; }
  else if (b < 384) { W = W2; asrc = as2; adst = ad2; P = P2; K = 128; H = 4; k = b - 256; }
  else              { W = W3; asrc = as3; adst = ad3; P = P3; K = 128; H = 1; k = b - 384; }
  __shared__ float red[2];
  const int c = threadIdx.x;
  for (int j = 0; j < 2 * H; ++j) {
    const int h = (j < H) ? j : j - H;
    const float* a = (j < H) ? asrc : adst;
    float pv = W[(size_t)k * (H * 128) + h * 128 + c] * a[h * 128 + c];
#pragma unroll
    for (int d = 1; d < 64; d <<= 1) pv += __shfl_xor(pv, d);
    if ((c & 63) == 0) red[c >> 6] = pv;
    __syncthreads();
    if (c == 0) P[j * K + k] = red[0] + red[1];
    __syncthreads();
  }
}

// M3t[c*128+k] = (bf16)(W3 @ L1)[k,c];  bm[c] = b3 @ L1[:,c] + l1b[c]
__global__ __launch_bounds__(256) void merge_w3l1(const float* __restrict__ W3,
                                                  const float* __restrict__ L1,
                                                  const float* __restrict__ b3,
                                                  const float* __restrict__ l1b,
                                                  bf16_t* __restrict__ M3t,
                                                  float* __restrict__ bm) {
  const int idx = blockIdx.x * 256 + threadIdx.x;
  const int k = idx >> 7, c = idx & 127;
  float s = 0.f;
  for (int m = 0; m < 128; ++m) s += W3[k * 128 + m] * L1[m * 128 + c];
  M3t[c * 128 + k] = (bf16_t)s;
  if (k == 0) {
    float t = l1b[c];
    for (int m = 0; m < 128; ++m) t += b3[m] * L1[m * 128 + c];
    bm[c] = t;
  }
}

// ---------------- fused cast + layer-1 alpha logits (wave per node) ----------------

__global__ __launch_bounds__(256) void cast_alpha1(const float* __restrict__ x,
                                                   const float* __restrict__ P,
                                                   bf16_t* __restrict__ xb,
                                                   float* __restrict__ asad) {
  const int wv = threadIdx.x >> 6, lane = threadIdx.x & 63;
  const int n = blockIdx.x * 4 + wv;
  const float4 v = *(const float4*)&x[(size_t)n * 256 + lane * 4];
  uint2 ov;
  ov.x = pack2bf(v.x, v.y);
  ov.y = pack2bf(v.z, v.w);
  *(uint2*)&xb[(size_t)n * 256 + lane * 4] = ov;
  float s[8];
#pragma unroll
  for (int j = 0; j < 8; ++j) {
    const float4 pj = *(const float4*)&P[j * 256 + lane * 4];
    s[j] = v.x * pj.x + v.y * pj.y + v.z * pj.z + v.w * pj.w;
  }
#pragma unroll
  for (int j = 0; j < 8; ++j)
#pragma unroll
    for (int d = 1; d < 64; d <<= 1) s[j] += __shfl_xor(s[j], d);
  if (lane == 0) {
#pragma unroll
    for (int j = 0; j < 8; ++j) asad[(size_t)n * 8 + j] = s[j];
  }
}

// ---------------- bf16 MFMA GEMM: C = act(A @ Bt^T + bias) ----------------
// ACT: 0=none, 1=relu, 2=sigmoid, 3=BN(eval)+relu

template <int TN, int ACT, typename OUT_T>
__global__ __launch_bounds__(256) void gemm_mfma(const bf16_t* __restrict__ A,
                                                 const bf16_t* __restrict__ Bt,
                                                 const float* __restrict__ bias,
                                                 const float* __restrict__ bng,
                                                 const float* __restrict__ bnb,
                                                 const float* __restrict__ bnm,
                                                 const float* __restrict__ bnv,
                                                 OUT_T* __restrict__ C,
                                                 int M, int N, int K) {
  constexpr int TM = 128, BK = 64;
  constexpr int MT = (TN == 128) ? 4 : 2;
  constexpr int NRB = (TN * BK * 2) / 4096;
  __shared__ __align__(16) bf16_t As[TM * BK];
  __shared__ __align__(16) bf16_t Bs[TN * BK];

  const int t = threadIdx.x;
  const int wave = t >> 6, lane = t & 63;
  const int ln15 = lane & 15, quad = lane >> 4;
  const int bm = blockIdx.x * TM;
  const int bn = blockIdx.y * TN;
  const int wm = (TN == 128) ? (wave >> 1) * 64 : wave * 32;
  const int wn = (TN == 128) ? (wave & 1) * 64 : 0;
  const int rowLimA = M - 1 - bm;
  const size_t strideAB = (size_t)K * 2;

  f32x4 acc[MT][4];
#pragma unroll
  for (int mi = 0; mi < MT; ++mi)
#pragma unroll
    for (int ni = 0; ni < 4; ++ni) acc[mi][ni] = (f32x4){0.f, 0.f, 0.f, 0.f};

  const char* gA = (const char*)(A + (size_t)bm * K);
  const char* gB = (const char*)(Bt + (size_t)bn * K);

  for (int k0 = 0; k0 < K; k0 += BK) {
#pragma unroll
    for (int r = 0; r < 4; ++r) {
      int base = (wave * 4 + r) * 1024;
      int flat = base + lane * 16;
      int row = flat >> 7;
      int grow = row < rowLimA ? row : rowLimA;
      const char* gp = gA + (size_t)grow * strideAB + (size_t)(k0 * 2) + (flat & 127);
      __builtin_amdgcn_global_load_lds((const AS1 void*)gp,
                                       (AS3 void*)((char*)As + base), 16, 0, 0);
    }
#pragma unroll
    for (int r = 0; r < NRB; ++r) {
      int base = (wave * NRB + r) * 1024;
      int flat = base + lane * 16;
      int row = flat >> 7;
      const char* gp = gB + (size_t)row * strideAB + (size_t)(k0 * 2) + (flat & 127);
      __builtin_amdgcn_global_load_lds((const AS1 void*)gp,
                                       (AS3 void*)((char*)Bs + base), 16, 0, 0);
    }
    __syncthreads();
#pragma unroll
    for (int kk = 0; kk < BK; kk += 32) {
      bf16x8 af[MT], bfr[4];
#pragma unroll
      for (int mi = 0; mi < MT; ++mi)
        af[mi] = *(const bf16x8*)&As[(wm + mi * 16 + ln15) * BK + kk + quad * 8];
#pragma unroll
      for (int ni = 0; ni < 4; ++ni)
        bfr[ni] = *(const bf16x8*)&Bs[(wn + ni * 16 + ln15) * BK + kk + quad * 8];
#pragma unroll
      for (int mi = 0; mi < MT; ++mi)
#pragma unroll
        for (int ni = 0; ni < 4; ++ni)
          acc[mi][ni] = __builtin_amdgcn_mfma_f32_16x16x32_bf16(af[mi], bfr[ni], acc[mi][ni], 0, 0, 0);
    }
    __syncthreads();
  }

#pragma unroll
  for (int mi = 0; mi < MT; ++mi) {
    int r0 = bm + wm + mi * 16 + quad * 4;
#pragma unroll
    for (int ni = 0; ni < 4; ++ni) {
      int c = bn + wn + ni * 16 + ln15;
      float bv = bias ? bias[c] : 0.f;
      float sc = 1.f, sh = 0.f;
      if (ACT == 3) {
        sc = bng[c] * rsqrtf(bnv[c] + 1e-5f);
        sh = bnb[c] - bnm[c] * sc;
      }
#pragma unroll
      for (int reg = 0; reg < 4; ++reg) {
        int r = r0 + reg;
        if (r < M) {
          float v = acc[mi][ni][reg] + bv;
          if (ACT == 1) v = fmaxf(v, 0.f);
          else if (ACT == 2) v = 1.f / (1.f + __expf(-v));
          else if (ACT == 3) v = fmaxf(v * sc + sh, 0.f);
          C[(size_t)r * N + c] = (OUT_T)v;
        }
      }
    }
  }
}

// ---------------- alpha logits for layers 2/3: asad[n, j] = f[n,:] . P[j,:] ----------

template <int K, int H>
__global__ __launch_bounds__(256) void alpha_gemm(const bf16_t* __restrict__ f,
                                                  const float* __restrict__ P,
                                                  float* __restrict__ asad) {
  constexpr int J = 2 * H;
  constexpr int KC = K / 64;
  const int wv = threadIdx.x >> 6, lane = threadIdx.x & 63;
  const int n = blockIdx.x * 4 + wv;
  float v[KC];
  if (KC == 4) {
    uint2 pv = *(const uint2*)&f[(size_t)n * K + lane * 4];
    v[0] = bflo(pv.x); v[1] = bfhi(pv.x); v[2] = bflo(pv.y); v[3] = bfhi(pv.y);
  } else {
    uint32_t pv = *(const uint32_t*)&f[(size_t)n * K + lane * 2];
    v[0] = bflo(pv); v[1] = bfhi(pv);
  }
  float s[J];
#pragma unroll
  for (int j = 0; j < J; ++j) {
    float acc = 0.f;
#pragma unroll
    for (int q = 0; q < KC; ++q) acc += v[q] * P[j * K + lane * KC + q];
    s[j] = acc;
  }
#pragma unroll
  for (int j = 0; j < J; ++j)
#pragma unroll
    for (int d = 1; d < 64; d <<= 1) s[j] += __shfl_xor(s[j], d);
  if (lane == 0) {
#pragma unroll
    for (int j = 0; j < J; ++j) asad[(size_t)n * J + j] = s[j];
  }
}

// ---------------- input-space GAT aggregation, H=4: wave per node, fused alpha -------
// agg[n, h*K + k] = sum_e alpha_e^h * f[src_e, k]

template <int K>
__global__ __launch_bounds__(256) void gat_agg_in4(const bf16_t* __restrict__ f,
                                                   const float* __restrict__ asad,
                                                   const int* __restrict__ rp,
                                                   const int* __restrict__ cs,
                                                   bf16_t* __restrict__ agg) {
  constexpr int KC = K / 64;  // bf16 per lane (4 or 2)
  const int wv = threadIdx.x >> 6, lane = threadIdx.x & 63;
  const int n = blockIdx.x * 4 + wv;
  __shared__ int sb[4][64];
  __shared__ float4 wl[4][64];

  const int r0 = rp[n], r1 = rp[n + 1];
  const int deg = r1 - r0;
  const float4 adv = *(const float4*)&asad[(size_t)n * 8 + 4];
  const char* fb = (const char*)f;
  const size_t loff = (size_t)lane * (KC * 2);

  float acc[4][KC];
#pragma unroll
  for (int j = 0; j < 4; ++j)
#pragma unroll
    for (int q = 0; q < KC; ++q) acc[j][q] = 0.f;

  auto edge_fma = [&](const char* gp, float4 w4) {
    if (KC == 4) {
      uint2 b = *(const uint2*)gp;
      float v0 = bflo(b.x), v1 = bfhi(b.x), v2 = bflo(b.y), v3 = bfhi(b.y);
      acc[0][0] += w4.x * v0; acc[0][1] += w4.x * v1; acc[0][2] += w4.x * v2; acc[0][3] += w4.x * v3;
      acc[1][0] += w4.y * v0; acc[1][1] += w4.y * v1; acc[1][2] += w4.y * v2; acc[1][3] += w4.y * v3;
      acc[2][0] += w4.z * v0; acc[2][1] += w4.z * v1; acc[2][2] += w4.z * v2; acc[2][3] += w4.z * v3;
      acc[3][0] += w4.w * v0; acc[3][1] += w4.w * v1; acc[3][2] += w4.w * v2; acc[3][3] += w4.w * v3;
    } else {
      uint32_t b = *(const uint32_t*)gp;
      float v0 = bflo(b), v1 = bfhi(b);
      acc[0][0] += w4.x * v0; acc[0][1] += w4.x * v1;
      acc[1][0] += w4.y * v0; acc[1][1] += w4.y * v1;
      acc[2][0] += w4.z * v0; acc[2][1] += w4.z * v1;
      acc[3][0] += w4.w * v0; acc[3][1] += w4.w * v1;
    }
  };

  if (deg <= 64) {
    const bool valid = lane < deg;
    int s = 0;
    float e0 = -1e30f, e1 = -1e30f, e2 = -1e30f, e3 = -1e30f;
    if (valid) {
      s = cs[r0 + lane];
      const float4 av = *(const float4*)&asad[(size_t)s * 8];
      e0 = lrelu(av.x + adv.x); e1 = lrelu(av.y + adv.y);
      e2 = lrelu(av.z + adv.z); e3 = lrelu(av.w + adv.w);
    }
    float m0 = e0, m1 = e1, m2 = e2, m3 = e3;
#pragma unroll
    for (int d = 1; d < 64; d <<= 1) {
      m0 = fmaxf(m0, __shfl_xor(m0, d)); m1 = fmaxf(m1, __shfl_xor(m1, d));
      m2 = fmaxf(m2, __shfl_xor(m2, d)); m3 = fmaxf(m3, __shfl_xor(m3, d));
    }
    float x0 = valid ? __expf(e0 - m0) : 0.f;
    float x1 = valid ? __expf(e1 - m1) : 0.f;
    float x2 = valid ? __expf(e2 - m2) : 0.f;
    float x3 = valid ? __expf(e3 - m3) : 0.f;
    float d0 = x0, d1 = x1, d2 = x2, d3 = x3;
#pragma unroll
    for (int d = 1; d < 64; d <<= 1) {
      d0 += __shfl_xor(d0, d); d1 += __shfl_xor(d1, d);
      d2 += __shfl_xor(d2, d); d3 += __shfl_xor(d3, d);
    }
    if (valid) {
      sb[wv][lane] = s * (K * 2);
      wl[wv][lane] = make_float4(x0 / (d0 + 1e-16f), x1 / (d1 + 1e-16f),
                                 x2 / (d2 + 1e-16f), x3 / (d3 + 1e-16f));
    }
    __builtin_amdgcn_wave_barrier();

    int g = 0;
    for (; g + 8 <= deg; g += 8) {  // 8-deep load pipeline
      const char* p[8];
      float4 w[8];
#pragma unroll
      for (int k = 0; k < 8; ++k) { p[k] = fb + (size_t)sb[wv][g + k] + loff; w[k] = wl[wv][g + k]; }
      if (KC == 4) {
        uint2 b[8];
#pragma unroll
        for (int k = 0; k < 8; ++k) b[k] = *(const uint2*)p[k];
#pragma unroll
        for (int k = 0; k < 8; ++k) {
          float v0 = bflo(b[k].x), v1 = bfhi(b[k].x), v2 = bflo(b[k].y), v3 = bfhi(b[k].y);
          acc[0][0] += w[k].x * v0; acc[0][1] += w[k].x * v1; acc[0][2] += w[k].x * v2; acc[0][3] += w[k].x * v3;
          acc[1][0] += w[k].y * v0; acc[1][1] += w[k].y * v1; acc[1][2] += w[k].y * v2; acc[1][3] += w[k].y * v3;
          acc[2][0] += w[k].z * v0; acc[2][1] += w[k].z * v1; acc[2][2] += w[k].z * v2; acc[2][3] += w[k].z * v3;
          acc[3][0] += w[k].w * v0; acc[3][1] += w[k].w * v1; acc[3][2] += w[k].w * v2; acc[3][3] += w[k].w * v3;
        }
      } else {
        uint32_t b[8];
#pragma unroll
        for (int k = 0; k < 8; ++k) b[k] = *(const uint32_t*)p[k];
#pragma unroll
        for (int k = 0; k < 8; ++k) {
          float v0 = bflo(b[k]), v1 = bfhi(b[k]);
          acc[0][0] += w[k].x * v0; acc[0][1] += w[k].x * v1;
          acc[1][0] += w[k].y * v0; acc[1][1] += w[k].y * v1;
          acc[2][0] += w[k].z * v0; acc[2][1] += w[k].z * v1;
          acc[3][0] += w[k].w * v0; acc[3][1] += w[k].w * v1;
        }
      }
    }
    for (; g < deg; ++g)
      edge_fma(fb + (size_t)sb[wv][g] + loff, wl[wv][g]);
  } else {
    // chunked fallback (deg > 64)
    float m0 = -1e30f, m1 = -1e30f, m2 = -1e30f, m3 = -1e30f;
    for (int i = r0 + lane; i < r1; i += 64) {
      const float4 av = *(const float4*)&asad[(size_t)cs[i] * 8];
      m0 = fmaxf(m0, lrelu(av.x + adv.x)); m1 = fmaxf(m1, lrelu(av.y + adv.y));
      m2 = fmaxf(m2, lrelu(av.z + adv.z)); m3 = fmaxf(m3, lrelu(av.w + adv.w));
    }
#pragma unroll
    for (int d = 1; d < 64; d <<= 1) {
      m0 = fmaxf(m0, __shfl_xor(m0, d)); m1 = fmaxf(m1, __shfl_xor(m1, d));
      m2 = fmaxf(m2, __shfl_xor(m2, d)); m3 = fmaxf(m3, __shfl_xor(m3, d));
    }
    float d0 = 0.f, d1 = 0.f, d2 = 0.f, d3 = 0.f;
    for (int i = r0 + lane; i < r1; i += 64) {
      const float4 av = *(const float4*)&asad[(size_t)cs[i] * 8];
      d0 += __expf(lrelu(av.x + adv.x) - m0); d1 += __expf(lrelu(av.y + adv.y) - m1);
      d2 += __expf(lrelu(av.z + adv.z) - m2); d3 += __expf(lrelu(av.w + adv.w) - m3);
    }
#pragma unroll
    for (int d = 1; d < 64; d <<= 1) {
      d0 += __shfl_xor(d0, d); d1 += __shfl_xor(d1, d);
      d2 += __shfl_xor(d2, d); d3 += __shfl_xor(d3, d);
    }
    const float i0 = 1.f / (d0 + 1e-16f), i1 = 1.f / (d1 + 1e-16f);
    const float i2 = 1.f / (d2 + 1e-16f), i3 = 1.f / (d3 + 1e-16f);
    for (int base = r0; base < r1; base += 64) {
      const int ne = min(64, r1 - base);
      if (lane < ne) {
        const int s = cs[base + lane];
        const float4 av = *(const float4*)&asad[(size_t)s * 8];
        sb[wv][lane] = s * (K * 2);
        wl[wv][lane] = make_float4(__expf(lrelu(av.x + adv.x) - m0) * i0,
                                   __expf(lrelu(av.y + adv.y) - m1) * i1,
                                   __expf(lrelu(av.z + adv.z) - m2) * i2,
                                   __expf(lrelu(av.w + adv.w) - m3) * i3);
      }
      __builtin_amdgcn_wave_barrier();
      for (int g = 0; g < ne; ++g)
        edge_fma(fb + (size_t)sb[wv][g] + loff, wl[wv][g]);
      __builtin_amdgcn_wave_barrier();
    }
  }

  // store agg row [4 heads][K]
#pragma unroll
  for (int j = 0; j < 4; ++j) {
    if (KC == 4) {
      uint2 ov;
      ov.x = pack2bf(acc[j][0], acc[j][1]);
      ov.y = pack2bf(acc[j][2], acc[j][3]);
      *(uint2*)&agg[(size_t)n * (4 * K) + j * K + lane * 4] = ov;
    } else {
      *(uint32_t*)&agg[(size_t)n * (4 * K) + j * K + lane * 2] = pack2bf(acc[j][0], acc[j][1]);
    }
  }
}

// ---------------- input-space GAT aggregation, H=1 (K=128): wave per node ------------

__global__ __launch_bounds__(256) void gat_agg_in1(const bf16_t* __restrict__ f,
                                                   const float* __restrict__ asad,
                                                   const int* __restrict__ rp,
                                                   const int* __restrict__ cs,
                                                   bf16_t* __restrict__ agg) {
  const int wv = threadIdx.x >> 6, lane = threadIdx.x & 63;
  const int n = blockIdx.x * 4 + wv;
  __shared__ int sb[4][64];
  __shared__ float wl[4][64];

  const int r0 = rp[n], r1 = rp[n + 1];
  const int deg = r1 - r0;
  const float adv = asad[(size_t)n * 2 + 1];
  const char* fb = (const char*)f;
  const size_t loff = (size_t)lane * 4;
  float a0 = 0.f, a1 = 0.f;

  auto fma2 = [&](uint32_t v, float w) { a0 += w * bflo(v); a1 += w * bfhi(v); };

  if (deg <= 64) {
    const bool valid = lane < deg;
    int s = 0;
    float e = -1e30f;
    if (valid) { s = cs[r0 + lane]; e = lrelu(asad[(size_t)s * 2] + adv); }
    float m = e;
#pragma unroll
    for (int d = 1; d < 64; d <<= 1) m = fmaxf(m, __shfl_xor(m, d));
    float x = valid ? __expf(e - m) : 0.f;
    float den = x;
#pragma unroll
    for (int d = 1; d < 64; d <<= 1) den += __shfl_xor(den, d);
    if (valid) { sb[wv][lane] = s * 256; wl[wv][lane] = x / (den + 1e-16f); }
    __builtin_amdgcn_wave_barrier();
    int g = 0;
    for (; g + 8 <= deg; g += 8) {
      uint32_t b[8];
      float w[8];
#pragma unroll
      for (int k = 0; k < 8; ++k) {
        b[k] = *(const uint32_t*)(fb + (size_t)sb[wv][g + k] + loff);
        w[k] = wl[wv][g + k];
      }
#pragma unroll
      for (int k = 0; k < 8; ++k) { a0 += w[k] * bflo(b[k]); a1 += w[k] * bfhi(b[k]); }
    }
    for (; g < deg; ++g)
      fma2(*(const uint32_t*)(fb + (size_t)sb[wv][g] + loff), wl[wv][g]);
  } else {
    float m = -1e30f;
    for (int i = r0 + lane; i < r1; i += 64) m = fmaxf(m, lrelu(asad[(size_t)cs[i] * 2] + adv));
#pragma unroll
    for (int d = 1; d < 64; d <<= 1) m = fmaxf(m, __shfl_xor(m, d));
    float den = 0.f;
    for (int i = r0 + lane; i < r1; i += 64) den += __expf(lrelu(asad[(size_t)cs[i] * 2] + adv) - m);
#pragma unroll
    for (int d = 1; d < 64; d <<= 1) den += __shfl_xor(den, d);
    const float dinv = 1.f / (den + 1e-16f);
    for (int base = r0; base < r1; base += 64) {
      const int ne = min(64, r1 - base);
      if (lane < ne) {
        const int s = cs[base + lane];
        sb[wv][lane] = s * 256;
        wl[wv][lane] = __expf(lrelu(asad[(size_t)s * 2] + adv) - m) * dinv;
      }
      __builtin_amdgcn_wave_barrier();
      for (int g = 0; g < ne; ++g)
        fma2(*(const uint32_t*)(fb + (size_t)sb[wv][g] + loff), wl[wv][g]);
      __builtin_amdgcn_wave_barrier();
    }
  }
  *(uint32_t*)&agg[(size_t)n * 128 + lane * 2] = pack2bf(a0, a1);
}

// ---------------- fused classifier tail: out = sig(relu(relu(A@M3t+bm)@l2+b2)@l3+b3) --
// A [M,128] bf16 (agg3). All intermediates in LDS. 64 KB total, 256 threads.

__global__ __launch_bounds__(256) void mlp_tail(const bf16_t* __restrict__ A,
                                                const bf16_t* __restrict__ M3t,  // [128,128]
                                                const float* __restrict__ bm,
                                                const bf16_t* __restrict__ l2t,  // [64,128]
                                                const float* __restrict__ l2b,
                                                const bf16_t* __restrict__ l3t,  // [64,64]
                                                const float* __restrict__ l3b,
                                                float* __restrict__ out, int M) {
  __shared__ __align__(16) bf16_t As[128 * 128];  // input -> H1 -> (first 16KB) H2
  __shared__ __align__(16) bf16_t Ws[128 * 128];  // M3t -> (W2 at 0, W3 at 8192)
  const int t = threadIdx.x, wave = t >> 6, lane = t & 63;
  const int ln15 = lane & 15, quad = lane >> 4;
  const int bmr = blockIdx.x * 128;
  const int rowLim = M - 1 - bmr;

  // stage input tile (32 KB) + M3t (32 KB)
#pragma unroll
  for (int r = 0; r < 8; ++r) {
    int base = (wave * 8 + r) * 1024;
    int flat = base + lane * 16;
    int row = flat >> 8;  // 256 B rows
    int grow = row < rowLim ? row : rowLim;
    const char* gp = (const char*)A + (size_t)grow * 256 + (flat & 255);
    __builtin_amdgcn_global_load_lds((const AS1 void*)gp,
                                     (AS3 void*)((char*)As + base), 16, 0, 0);
  }
#pragma unroll
  for (int r = 0; r < 8; ++r) {
    int base = (wave * 8 + r) * 1024;
    __builtin_amdgcn_global_load_lds((const AS1 void*)((const char*)M3t + base + lane * 16),
                                     (AS3 void*)((char*)Ws + base), 16, 0, 0);
  }
  __syncthreads();

  // ---- stage 1: H1 = relu(A @ M3t^T + bm), 128x128 ----
  const int wm = wave * 32;
  f32x4 a1[2][8];
#pragma unroll
  for (int mi = 0; mi < 2; ++mi)
#pragma unroll
    for (int ni = 0; ni < 8; ++ni) a1[mi][ni] = (f32x4){0.f, 0.f, 0.f, 0.f};
#pragma unroll
  for (int kk = 0; kk < 128; kk += 32) {
    bf16x8 af[2];
#pragma unroll
    for (int mi = 0; mi < 2; ++mi)
      af[mi] = *(const bf16x8*)&As[(wm + mi * 16 + ln15) * 128 + kk + quad * 8];
#pragma unroll
    for (int ni = 0; ni < 8; ++ni) {
      bf16x8 bf = *(const bf16x8*)&Ws[(ni * 16 + ln15) * 128 + kk + quad * 8];
#pragma unroll
      for (int mi = 0; mi < 2; ++mi)
        a1[mi][ni] = __builtin_amdgcn_mfma_f32_16x16x32_bf16(af[mi], bf, a1[mi][ni], 0, 0, 0);
    }
  }
  __syncthreads();  // all reads of As/Ws done

  // stage W2 (16 KB at Ws+0) and W3 (8 KB at Ws+8192 elems)
#pragma unroll
  for (int r = 0; r < 4; ++r) {
    int base = (wave * 4 + r) * 1024;
    __builtin_amdgcn_global_load_lds((const AS1 void*)((const char*)l2t + base + lane * 16),
                                     (AS3 void*)((char*)Ws + base), 16, 0, 0);
  }
#pragma unroll
  for (int r = 0; r < 2; ++r) {
    int base = (wave * 2 + r) * 1024;
    __builtin_amdgcn_global_load_lds((const AS1 void*)((const char*)l3t + base + lane * 16),
                                     (AS3 void*)((char*)Ws + 8192 * 2 + base), 16, 0, 0);
  }
  // write H1 into As
#pragma unroll
  for (int mi = 0; mi < 2; ++mi) {
    int r0 = wm + mi * 16 + quad * 4;
#pragma unroll
    for (int ni = 0; ni < 8; ++ni) {
      int c = ni * 16 + ln15;
      float bv = bm[c];
#pragma unroll
      for (int reg = 0; reg < 4; ++reg)
        As[(r0 + reg) * 128 + c] = (bf16_t)fmaxf(a1[mi][ni][reg] + bv, 0.f);
    }
  }
  __syncthreads();

  // ---- stage 2: H2 = relu(H1 @ l2t^T + l2b), 128x64 ----
  f32x4 a2[2][4];
#pragma unroll
  for (int mi = 0; mi < 2; ++mi)
#pragma unroll
    for (int ni = 0; ni < 4; ++ni) a2[mi][ni] = (f32x4){0.f, 0.f, 0.f, 0.f};
#pragma unroll
  for (int kk = 0; kk < 128; kk += 32) {
    bf16x8 af[2];
#pragma unroll
    for (int mi = 0; mi < 2; ++mi)
      af[mi] = *(const bf16x8*)&As[(wm + mi * 16 + ln15) * 128 + kk + quad * 8];
#pragma unroll
    for (int ni = 0; ni < 4; ++ni) {
      bf16x8 bf = *(const bf16x8*)&Ws[(ni * 16 + ln15) * 128 + kk + quad * 8];
#pragma unroll
      for (int mi = 0; mi < 2; ++mi)
        a2[mi][ni] = __builtin_amdgcn_mfma_f32_16x16x32_bf16(af[mi], bf, a2[mi][ni], 0, 0, 0);
    }
  }
  __syncthreads();  // all reads of H1 done

  // write H2 into As[0 : 128*64]
#pragma unroll
  for (int mi = 0; mi < 2; ++mi) {
    int r0 = wm + mi * 16 + quad * 4;
#pragma unroll
    for (int ni = 0; ni < 4; ++ni) {
      int c = ni * 16 + ln15;
      float bv = l2b[c];
#pragma unroll
      for (int reg = 0; reg < 4; ++reg)
        As[(r0 + reg) * 64 + c] = (bf16_t)fmaxf(a2[mi][ni][reg] + bv, 0.f);
    }
  }
  __syncthreads();

  // ---- stage 3: out = sigmoid(H2 @ l3t^T + l3b), 128x64 ----
  f32x4 a3[2][4];
#pragma unroll
  for (int mi = 0; mi < 2; ++mi)
#pragma unroll
    for (int ni = 0; ni < 4; ++ni) a3[mi][ni] = (f32x4){0.f, 0.f, 0.f, 0.f};
#pragma unroll
  for (int kk = 0; kk < 64; kk += 32) {
    bf16x8 af[2];
#pragma unroll
    for (int mi = 0; mi < 2; ++mi)
      af[mi] = *(const bf16x8*)&As[(wm + mi * 16 + ln15) * 64 + kk + quad * 8];
#pragma unroll
    for (int ni = 0; ni < 4; ++ni) {
      bf16x8 bf = *(const bf16x8*)&Ws[8192 + (ni * 16 + ln15) * 64 + kk + quad * 8];
#pragma unroll
      for (int mi = 0; mi < 2; ++mi)
        a3[mi][ni] = __builtin_amdgcn_mfma_f32_16x16x32_bf16(af[mi], bf, a3[mi][ni], 0, 0, 0);
    }
  }
#pragma unroll
  for (int mi = 0; mi < 2; ++mi) {
    int r0 = wm + mi * 16 + quad * 4;
#pragma unroll
    for (int ni = 0; ni < 4; ++ni) {
      int c = ni * 16 + ln15;
      float bv = l3b[c];
#pragma unroll
      for (int reg = 0; reg < 4; ++reg) {
        int r = bmr + r0 + reg;
        if (r < M) {
          float v = a3[mi][ni][reg] + bv;
          out[(size_t)r * 64 + c] = 1.f / (1.f + __expf(-v));
        }
      }
    }
  }
}

// ---------------- launch ----------------

extern "C" void kernel_launch(void* const* d_in, const int* in_sizes, int n_in,
                              void* d_out, int out_size, void* d_ws, size_t ws_size,
                              hipStream_t stream) {
  const float* x      = (const float*)d_in[0];
  const int*   ei     = (const int*)d_in[1];
  const float* W1     = (const float*)d_in[2];
  const float* a_src1 = (const float*)d_in[3];
  const float* a_dst1 = (const float*)d_in[4];
  const float* b1     = (const float*)d_in[5];
  const float* W2     = (const float*)d_in[6];
  const float* a_src2 = (const float*)d_in[7];
  const float* a_dst2 = (const float*)d_in[8];
  const float* b2     = (const float*)d_in[9];
  const float* W3     = (const float*)d_in[10];
  const float* a_src3 = (const float*)d_in[11];
  const float* a_dst3 = (const float*)d_in[12];
  const float* b3     = (const float*)d_in[13];
  const float* bn1g = (const float*)d_in[14];
  const float* bn1b = (const float*)d_in[15];
  const float* bn1m = (const float*)d_in[16];
  const float* bn1v = (const float*)d_in[17];
  const float* bn2g = (const float*)d_in[18];
  const float* bn2b = (const float*)d_in[19];
  const float* bn2m = (const float*)d_in[20];
  const float* bn2v = (const float*)d_in[21];
  const float* l1w = (const float*)d_in[22];
  const float* l1b = (const float*)d_in[23];
  const float* l2w = (const float*)d_in[24];
  const float* l2b = (const float*)d_in[25];
  const float* l3w = (const float*)d_in[26];
  const float* l3b = (const float*)d_in[27];
  float* out = (float*)d_out;

  const int N = NN;
  const int E = in_sizes[1] / 2;
  const int ET = E + N;

  char* p = (char*)d_ws;
  auto carve = [&](size_t bytes) {
    char* q = p;
    p += (bytes + 255) & ~(size_t)255;
    return q;
  };
  bf16_t* xb    = (bf16_t*)carve((size_t)N * 256 * 2);   // 10.24 MB
  bf16_t* aggb  = (bf16_t*)carve((size_t)N * 1024 * 2);  // 40.96 MB
  bf16_t* f1b   = (bf16_t*)carve((size_t)N * 128 * 2);
  bf16_t* f2b   = (bf16_t*)carve((size_t)N * 128 * 2);
  float* asad   = (float*)carve((size_t)N * 8 * 4);
  int* cnt      = (int*)carve((size_t)N * 4);
  int* cursor   = (int*)carve((size_t)N * 4);
  int* row_ptr  = (int*)carve((size_t)(N + 1) * 4);
  int* col      = (int*)carve((size_t)ET * 4);
  bf16_t* Ws1t  = (bf16_t*)carve((size_t)128 * 1024 * 2);
  bf16_t* Ws2t  = (bf16_t*)carve((size_t)128 * 512 * 2);
  bf16_t* M3t   = (bf16_t*)carve((size_t)128 * 128 * 2);
  bf16_t* l2t   = (bf16_t*)carve((size_t)64 * 128 * 2);
  bf16_t* l3t   = (bf16_t*)carve((size_t)64 * 64 * 2);
  float* P1     = (float*)carve((size_t)8 * 256 * 4);
  float* P2     = (float*)carve((size_t)8 * 128 * 4);
  float* P3     = (float*)carve((size_t)2 * 128 * 4);
  float* bm     = (float*)carve((size_t)128 * 4);
  (void)ws_size; (void)n_in; (void)out_size;

  // --- CSR build ---
  hipMemsetAsync(cnt, 0, (size_t)N * 4, stream);
  int eb = (ET + 255) / 256;
  hist_kernel<<<eb, 256, 0, stream>>>(ei, E, N, cnt);
  scan_kernel<<<1, 1024, 0, stream>>>(cnt, row_ptr, cursor, N);
  scatter_kernel<<<eb, 256, 0, stream>>>(ei, E, N, cursor, col);

  // --- prep ---
  WPack wp;
  wp.d[0] = {W1,  Ws1t, 256, 128, 4, 0.25f, 0};
  wp.d[1] = {W2,  Ws2t, 128, 128, 4, 0.25f, 128};
  wp.d[2] = {l2w, l2t,  128, 64,  1, 1.0f,  192};
  wp.d[3] = {l3w, l3t,  64,  64,  1, 1.0f,  200};
  wprep<<<204, dim3(32, 8), 0, stream>>>(wp);
  alpha_proj_all<<<512, 128, 0, stream>>>(W1, a_src1, a_dst1, W2, a_src2, a_dst2,
                                          W3, a_src3, a_dst3, P1, P2, P3);
  merge_w3l1<<<64, 256, 0, stream>>>(W3, l1w, b3, l1b, M3t, bm);

  const int gm = (N + 127) / 128;  // 157
  const int ab = N / 4;            // 5000

  // --- GAT layer 1 (fused cast + alpha; input-space aggregation) ---
  cast_alpha1<<<ab, 256, 0, stream>>>(x, P1, xb, asad);
  gat_agg_in4<256><<<ab, 256, 0, stream>>>(xb, asad, row_ptr, col, aggb);
  gemm_mfma<64, 3, bf16_t><<<dim3(gm, 2), 256, 0, stream>>>(
      aggb, Ws1t, b1, bn1g, bn1b, bn1m, bn1v, f1b, N, 128, 1024);

  // --- GAT layer 2 ---
  alpha_gemm<128, 4><<<ab, 256, 0, stream>>>(f1b, P2, asad);
  gat_agg_in4<128><<<ab, 256, 0, stream>>>(f1b, asad, row_ptr, col, aggb);
  gemm_mfma<64, 3, bf16_t><<<dim3(gm, 2), 256, 0, stream>>>(
      aggb, Ws2t, b2, bn2g, bn2b, bn2m, bn2v, f2b, N, 128, 512);

  // --- GAT layer 3 (H=1) + fused classifier tail ---
  alpha_gemm<128, 1><<<ab, 256, 0, stream>>>(f2b, P3, asad);
  gat_agg_in1<<<ab, 256, 0, stream>>>(f2b, asad, row_ptr, col, aggb);
  mlp_tail<<<gm, 256, 0, stream>>>(aggb, M3t, bm, l2t, l2b, l3t, l3b, out, N);
}

// Round 8
// 341.056 us; speedup vs baseline: 1.1699x; 1.0187x over previous
//
#include <hip/hip_runtime.h>
#include <cstdint>
#include <cstddef>

#define NN 20000

typedef __bf16 bf16_t;
typedef __bf16 bf16x8 __attribute__((ext_vector_type(8)));
typedef float f32x4 __attribute__((ext_vector_type(4)));

#define AS1 __attribute__((address_space(1)))
#define AS3 __attribute__((address_space(3)))

__device__ __forceinline__ float lrelu(float x) { return x >= 0.f ? x : 0.2f * x; }
__device__ __forceinline__ float bflo(uint32_t u) { return __uint_as_float(u << 16); }
__device__ __forceinline__ float bfhi(uint32_t u) { return __uint_as_float(u & 0xffff0000u); }

__device__ __forceinline__ uint32_t pack2bf(float a, float b) {
  bf16_t x = (bf16_t)a, y = (bf16_t)b;
  uint16_t ux = __builtin_bit_cast(uint16_t, x);
  uint16_t uy = __builtin_bit_cast(uint16_t, y);
  return (uint32_t)ux | ((uint32_t)uy << 16);
}

// ---------------- CSR scan (unchanged) ----------------

__global__ __launch_bounds__(1024) void scan_kernel(const int* __restrict__ cnt,
                                                    int* __restrict__ row_ptr,
                                                    int* __restrict__ cursor, int n) {
  __shared__ int wsum[16];
  const int t = threadIdx.x;
  const int lane = t & 63, w = t >> 6;
  int carry = 0;
  for (int base = 0; base < n; base += 1024) {
    int i = base + t;
    int v = (i < n) ? cnt[i] : 0;
    int x = v;
#pragma unroll
    for (int d = 1; d < 64; d <<= 1) {
      int y = __shfl_up(x, d);
      if (lane >= d) x += y;
    }
    if (lane == 63) wsum[w] = x;
    __syncthreads();
    if (t < 16) {
      int s = wsum[t];
#pragma unroll
      for (int d = 1; d < 16; d <<= 1) {
        int y = __shfl_up(s, d);
        if (t >= d) s += y;
      }
      wsum[t] = s;
    }
    __syncthreads();
    int blocksum = wsum[15];
    int wprefix = (w == 0) ? 0 : wsum[w - 1];
    int excl = carry + wprefix + (x - v);
    if (i < n) { row_ptr[i] = excl; cursor[i] = excl; }
    carry += blocksum;
    __syncthreads();
  }
  if (t == 0) row_ptr[n] = carry;
}

// ---------------- prep mega-kernel ----------------
// block ranges: [0,204) wprep | [204,716) alpha_proj | [716,780) merge_w3l1
//               [780,780+EB) hist | [780+EB, +196) zero asadB/C

struct WDesc { const float* W; bf16_t* Bt; int K; int Cw; int H; float scale; int b0; };
struct WPack { WDesc d[4]; };

struct Prep1Args {
  WPack wp;
  const float *W1, *as1, *ad1, *W2, *as2, *ad2, *W3, *as3, *ad3;
  float *P1, *P2, *P3;
  const float *W3m, *L1w, *b3v, *l1b;
  bf16_t* M3t; float* bm;
  const int* ei; int E, N, EB;
  int* cnt;
  float* zbuf; int zcount;
};

__global__ __launch_bounds__(256) void prep1(Prep1Args a) {
  __shared__ float tile[32][33];
  const int b = blockIdx.x;
  const int t = threadIdx.x;

  if (b < 204) {
    // ---- weight transpose/cast ----
    int i = 3;
#pragma unroll
    for (int k = 2; k >= 0; --k)
      if (b < a.wp.d[k + 1].b0) i = k;
    const WDesc de = a.wp.d[i];
    const int bi = b - de.b0;
    const int ktiles = de.K / 32;
    const int kt = bi % ktiles, rt = bi / ktiles;
    const int gc = rt * 32;
    const int h = gc / de.Cw, c0 = gc % de.Cw;
    const int tx = t & 31, ty = t >> 5;
#pragma unroll
    for (int r = 0; r < 32; r += 8)
      tile[ty + r][tx] = de.W[(size_t)(kt * 32 + ty + r) * (de.H * de.Cw) + h * de.Cw + c0 + tx];
    __syncthreads();
#pragma unroll
    for (int r = 0; r < 32; r += 8)
      de.Bt[(size_t)(c0 + ty + r) * (de.H * de.K) + h * de.K + kt * 32 + tx] =
          (bf16_t)(de.scale * tile[tx][ty + r]);
  } else if (b < 716) {
    // ---- alpha projections: P[j*K+k] = sum_c W[k, h*128+c] * a_j[h*128+c] ----
    const int kk = b - 204;
    const float *W, *asrc, *adst;
    float* P;
    int K, H, k;
    if (kk < 256)      { W = a.W1; asrc = a.as1; adst = a.ad1; P = a.P1; K = 256; H = 4; k = kk; }
    else if (kk < 384) { W = a.W2; asrc = a.as2; adst = a.ad2; P = a.P2; K = 128; H = 4; k = kk - 256; }
    else               { W = a.W3; asrc = a.as3; adst = a.ad3; P = a.P3; K = 128; H = 1; k = kk - 384; }
    for (int j = 0; j < 2 * H; ++j) {
      const int h = (j < H) ? j : j - H;
      const float* av = (j < H) ? asrc : adst;
      float pv = 0.f;
      if (t < 128) pv = W[(size_t)k * (H * 128) + h * 128 + t] * av[h * 128 + t];
#pragma unroll
      for (int d = 1; d < 64; d <<= 1) pv += __shfl_xor(pv, d);
      if (t == 0 || t == 64) tile[0][t >> 6] = pv;
      __syncthreads();
      if (t == 0) P[j * K + k] = tile[0][0] + tile[0][1];
      __syncthreads();
    }
  } else if (b < 780) {
    // ---- merge W3 @ L1 ----
    const int idx = (b - 716) * 256 + t;
    const int k = idx >> 7, c = idx & 127;
    float s = 0.f;
    for (int m = 0; m < 128; ++m) s += a.W3m[k * 128 + m] * a.L1w[m * 128 + c];
    a.M3t[c * 128 + k] = (bf16_t)s;
    if (k == 0) {
      float tt = a.l1b[c];
      for (int m = 0; m < 128; ++m) tt += a.b3v[m] * a.L1w[m * 128 + c];
      a.bm[c] = tt;
    }
  } else if (b < 780 + a.EB) {
    // ---- degree histogram ----
    const int i = (b - 780) * 256 + t;
    if (i < a.E + a.N) {
      int dst = (i < a.E) ? a.ei[a.E + i] : (i - a.E);
      atomicAdd(&a.cnt[dst], 1);
    }
  } else {
    // ---- zero asadB/asadC ----
    const int i = (b - 780 - a.EB) * 256 + t;
    if (i < a.zcount) ((float4*)a.zbuf)[i] = make_float4(0.f, 0.f, 0.f, 0.f);
  }
}

// ---------------- scatter + fused cast+layer1-alpha ----------------

__global__ __launch_bounds__(256) void scatter_cast(const int* __restrict__ ei, int E, int N,
                                                    int EB, int* __restrict__ cursor,
                                                    int* __restrict__ col,
                                                    const float* __restrict__ x,
                                                    const float* __restrict__ P1,
                                                    bf16_t* __restrict__ xb,
                                                    float* __restrict__ asadA) {
  const int b = blockIdx.x, t = threadIdx.x;
  if (b < EB) {
    const int i = b * 256 + t;
    if (i < E + N) {
      int src, dst;
      if (i < E) { src = ei[i]; dst = ei[E + i]; }
      else       { src = i - E; dst = src; }
      int slot = atomicAdd(&cursor[dst], 1);
      col[slot] = src;
    }
  } else {
    const int wv = t >> 6, lane = t & 63;
    const int n = (b - EB) * 4 + wv;
    const float4 v = *(const float4*)&x[(size_t)n * 256 + lane * 4];
    uint2 ov;
    ov.x = pack2bf(v.x, v.y);
    ov.y = pack2bf(v.z, v.w);
    *(uint2*)&xb[(size_t)n * 256 + lane * 4] = ov;
    float s[8];
#pragma unroll
    for (int j = 0; j < 8; ++j) {
      const float4 pj = *(const float4*)&P1[j * 256 + lane * 4];
      s[j] = v.x * pj.x + v.y * pj.y + v.z * pj.z + v.w * pj.w;
    }
#pragma unroll
    for (int j = 0; j < 8; ++j)
#pragma unroll
      for (int d = 1; d < 64; d <<= 1) s[j] += __shfl_xor(s[j], d);
    if (lane == 0) {
#pragma unroll
      for (int j = 0; j < 8; ++j) asadA[(size_t)n * 8 + j] = s[j];
    }
  }
}

// ---------------- bf16 MFMA GEMM: C = act(A @ Bt^T + bias), optional fused alpha ------
// ACT: 1=relu, 3=BN(eval)+relu. FJ: 0 none, 8/2 = alpha dims accumulated into asad_o.

template <int TN, int ACT, int FJ, typename OUT_T>
__global__ __launch_bounds__(256) void gemm_mfma(const bf16_t* __restrict__ A,
                                                 const bf16_t* __restrict__ Bt,
                                                 const float* __restrict__ bias,
                                                 const float* __restrict__ bng,
                                                 const float* __restrict__ bnb,
                                                 const float* __restrict__ bnm,
                                                 const float* __restrict__ bnv,
                                                 const float* __restrict__ P,
                                                 float* __restrict__ asad_o,
                                                 OUT_T* __restrict__ C,
                                                 int M, int N, int K) {
  constexpr int TM = 128, BK = 64;
  constexpr int MT = (TN == 128) ? 4 : 2;
  constexpr int NRB = (TN * BK * 2) / 4096;
  __shared__ __align__(16) bf16_t As[TM * BK];
  __shared__ __align__(16) bf16_t Bs[TN * BK];

  const int t = threadIdx.x;
  const int wave = t >> 6, lane = t & 63;
  const int ln15 = lane & 15, quad = lane >> 4;
  const int bm = blockIdx.x * TM;
  const int bn = blockIdx.y * TN;
  const int wm = (TN == 128) ? (wave >> 1) * 64 : wave * 32;
  const int wn = (TN == 128) ? (wave & 1) * 64 : 0;
  const int rowLimA = M - 1 - bm;
  const size_t strideAB = (size_t)K * 2;

  f32x4 acc[MT][4];
#pragma unroll
  for (int mi = 0; mi < MT; ++mi)
#pragma unroll
    for (int ni = 0; ni < 4; ++ni) acc[mi][ni] = (f32x4){0.f, 0.f, 0.f, 0.f};

  const char* gA = (const char*)(A + (size_t)bm * K);
  const char* gB = (const char*)(Bt + (size_t)bn * K);

  for (int k0 = 0; k0 < K; k0 += BK) {
#pragma unroll
    for (int r = 0; r < 4; ++r) {
      int base = (wave * 4 + r) * 1024;
      int flat = base + lane * 16;
      int row = flat >> 7;
      int grow = row < rowLimA ? row : rowLimA;
      const char* gp = gA + (size_t)grow * strideAB + (size_t)(k0 * 2) + (flat & 127);
      __builtin_amdgcn_global_load_lds((const AS1 void*)gp,
                                       (AS3 void*)((char*)As + base), 16, 0, 0);
    }
#pragma unroll
    for (int r = 0; r < NRB; ++r) {
      int base = (wave * NRB + r) * 1024;
      int flat = base + lane * 16;
      int row = flat >> 7;
      const char* gp = gB + (size_t)row * strideAB + (size_t)(k0 * 2) + (flat & 127);
      __builtin_amdgcn_global_load_lds((const AS1 void*)gp,
                                       (AS3 void*)((char*)Bs + base), 16, 0, 0);
    }
    __syncthreads();
#pragma unroll
    for (int kk = 0; kk < BK; kk += 32) {
      bf16x8 af[MT], bfr[4];
#pragma unroll
      for (int mi = 0; mi < MT; ++mi)
        af[mi] = *(const bf16x8*)&As[(wm + mi * 16 + ln15) * BK + kk + quad * 8];
#pragma unroll
      for (int ni = 0; ni < 4; ++ni)
        bfr[ni] = *(const bf16x8*)&Bs[(wn + ni * 16 + ln15) * BK + kk + quad * 8];
#pragma unroll
      for (int mi = 0; mi < MT; ++mi)
#pragma unroll
        for (int ni = 0; ni < 4; ++ni)
          acc[mi][ni] = __builtin_amdgcn_mfma_f32_16x16x32_bf16(af[mi], bfr[ni], acc[mi][ni], 0, 0, 0);
    }
    __syncthreads();
  }

  float vs[MT][4][4];
#pragma unroll
  for (int mi = 0; mi < MT; ++mi) {
    int r0 = bm + wm + mi * 16 + quad * 4;
#pragma unroll
    for (int ni = 0; ni < 4; ++ni) {
      int c = bn + wn + ni * 16 + ln15;
      float bv = bias ? bias[c] : 0.f;
      float sc = 1.f, sh = 0.f;
      if (ACT == 3) {
        sc = bng[c] * rsqrtf(bnv[c] + 1e-5f);
        sh = bnb[c] - bnm[c] * sc;
      }
#pragma unroll
      for (int reg = 0; reg < 4; ++reg) {
        float v = acc[mi][ni][reg] + bv;
        if (ACT == 1) v = fmaxf(v, 0.f);
        else if (ACT == 3) v = fmaxf(v * sc + sh, 0.f);
        vs[mi][ni][reg] = v;
        int r = r0 + reg;
        if (r < M) C[(size_t)r * N + c] = (OUT_T)v;
      }
    }
  }

  if (FJ > 0) {
    // fused next-layer alpha logits: asad_o[r*FJ+j] += sum_c vs[r][c] * P[j*N+c]
#pragma unroll
    for (int mi = 0; mi < MT; ++mi) {
#pragma unroll
      for (int reg = 0; reg < 4; ++reg) {
        int r = bm + wm + mi * 16 + quad * 4 + reg;
#pragma unroll
        for (int j = 0; j < FJ; ++j) {
          float s = 0.f;
#pragma unroll
          for (int ni = 0; ni < 4; ++ni) {
            int c = bn + wn + ni * 16 + ln15;
            s += vs[mi][ni][reg] * P[j * N + c];
          }
          s += __shfl_xor(s, 1);
          s += __shfl_xor(s, 2);
          s += __shfl_xor(s, 4);
          s += __shfl_xor(s, 8);
          if (ln15 == 0 && r < M) atomicAdd(&asad_o[(size_t)r * FJ + j], s);
        }
      }
    }
  }
}

// ---------------- input-space GAT aggregation, H=4: wave/node, 2 nodes/block ---------

template <int K>
__global__ __launch_bounds__(128) void gat_agg_in4(const bf16_t* __restrict__ f,
                                                   const float* __restrict__ asad,
                                                   const int* __restrict__ rp,
                                                   const int* __restrict__ cs,
                                                   bf16_t* __restrict__ agg) {
  constexpr int KC = K / 64;  // bf16 per lane (4 or 2)
  const int wv = threadIdx.x >> 6, lane = threadIdx.x & 63;
  const int n = blockIdx.x * 2 + wv;
  __shared__ int sb[2][64];
  __shared__ float4 wl[2][64];

  const int r0 = rp[n], r1 = rp[n + 1];
  const int deg = r1 - r0;
  const float4 adv = *(const float4*)&asad[(size_t)n * 8 + 4];
  const char* fb = (const char*)f;
  const size_t loff = (size_t)lane * (KC * 2);

  float acc[4][KC];
#pragma unroll
  for (int j = 0; j < 4; ++j)
#pragma unroll
    for (int q = 0; q < KC; ++q) acc[j][q] = 0.f;

  auto edge_fma = [&](const char* gp, float4 w4) {
    if (KC == 4) {
      uint2 b = *(const uint2*)gp;
      float v0 = bflo(b.x), v1 = bfhi(b.x), v2 = bflo(b.y), v3 = bfhi(b.y);
      acc[0][0] += w4.x * v0; acc[0][1] += w4.x * v1; acc[0][2] += w4.x * v2; acc[0][3] += w4.x * v3;
      acc[1][0] += w4.y * v0; acc[1][1] += w4.y * v1; acc[1][2] += w4.y * v2; acc[1][3] += w4.y * v3;
      acc[2][0] += w4.z * v0; acc[2][1] += w4.z * v1; acc[2][2] += w4.z * v2; acc[2][3] += w4.z * v3;
      acc[3][0] += w4.w * v0; acc[3][1] += w4.w * v1; acc[3][2] += w4.w * v2; acc[3][3] += w4.w * v3;
    } else {
      uint32_t b = *(const uint32_t*)gp;
      float v0 = bflo(b), v1 = bfhi(b);
      acc[0][0] += w4.x * v0; acc[0][1] += w4.x * v1;
      acc[1][0] += w4.y * v0; acc[1][1] += w4.y * v1;
      acc[2][0] += w4.z * v0; acc[2][1] += w4.z * v1;
      acc[3][0] += w4.w * v0; acc[3][1] += w4.w * v1;
    }
  };

  if (deg <= 64) {
    const bool valid = lane < deg;
    int s = 0;
    float e0 = -1e30f, e1 = -1e30f, e2 = -1e30f, e3 = -1e30f;
    if (valid) {
      s = cs[r0 + lane];
      const float4 av = *(const float4*)&asad[(size_t)s * 8];
      e0 = lrelu(av.x + adv.x); e1 = lrelu(av.y + adv.y);
      e2 = lrelu(av.z + adv.z); e3 = lrelu(av.w + adv.w);
    }
    float m0 = e0, m1 = e1, m2 = e2, m3 = e3;
#pragma unroll
    for (int d = 1; d < 64; d <<= 1) {
      m0 = fmaxf(m0, __shfl_xor(m0, d)); m1 = fmaxf(m1, __shfl_xor(m1, d));
      m2 = fmaxf(m2, __shfl_xor(m2, d)); m3 = fmaxf(m3, __shfl_xor(m3, d));
    }
    float x0 = valid ? __expf(e0 - m0) : 0.f;
    float x1 = valid ? __expf(e1 - m1) : 0.f;
    float x2 = valid ? __expf(e2 - m2) : 0.f;
    float x3 = valid ? __expf(e3 - m3) : 0.f;
    float d0 = x0, d1 = x1, d2 = x2, d3 = x3;
#pragma unroll
    for (int d = 1; d < 64; d <<= 1) {
      d0 += __shfl_xor(d0, d); d1 += __shfl_xor(d1, d);
      d2 += __shfl_xor(d2, d); d3 += __shfl_xor(d3, d);
    }
    if (valid) {
      sb[wv][lane] = s * (K * 2);
      wl[wv][lane] = make_float4(x0 / (d0 + 1e-16f), x1 / (d1 + 1e-16f),
                                 x2 / (d2 + 1e-16f), x3 / (d3 + 1e-16f));
    }
    __builtin_amdgcn_wave_barrier();

    int g = 0;
    for (; g + 8 <= deg; g += 8) {  // 8-deep load pipeline
      const char* p[8];
      float4 w[8];
#pragma unroll
      for (int k = 0; k < 8; ++k) { p[k] = fb + (size_t)sb[wv][g + k] + loff; w[k] = wl[wv][g + k]; }
      if (KC == 4) {
        uint2 b[8];
#pragma unroll
        for (int k = 0; k < 8; ++k) b[k] = *(const uint2*)p[k];
#pragma unroll
        for (int k = 0; k < 8; ++k) {
          float v0 = bflo(b[k].x), v1 = bfhi(b[k].x), v2 = bflo(b[k].y), v3 = bfhi(b[k].y);
          acc[0][0] += w[k].x * v0; acc[0][1] += w[k].x * v1; acc[0][2] += w[k].x * v2; acc[0][3] += w[k].x * v3;
          acc[1][0] += w[k].y * v0; acc[1][1] += w[k].y * v1; acc[1][2] += w[k].y * v2; acc[1][3] += w[k].y * v3;
          acc[2][0] += w[k].z * v0; acc[2][1] += w[k].z * v1; acc[2][2] += w[k].z * v2; acc[2][3] += w[k].z * v3;
          acc[3][0] += w[k].w * v0; acc[3][1] += w[k].w * v1; acc[3][2] += w[k].w * v2; acc[3][3] += w[k].w * v3;
        }
      } else {
        uint32_t b[8];
#pragma unroll
        for (int k = 0; k < 8; ++k) b[k] = *(const uint32_t*)p[k];
#pragma unroll
        for (int k = 0; k < 8; ++k) {
          float v0 = bflo(b[k]), v1 = bfhi(b[k]);
          acc[0][0] += w[k].x * v0; acc[0][1] += w[k].x * v1;
          acc[1][0] += w[k].y * v0; acc[1][1] += w[k].y * v1;
          acc[2][0] += w[k].z * v0; acc[2][1] += w[k].z * v1;
          acc[3][0] += w[k].w * v0; acc[3][1] += w[k].w * v1;
        }
      }
    }
    for (; g < deg; ++g)
      edge_fma(fb + (size_t)sb[wv][g] + loff, wl[wv][g]);
  } else {
    // chunked fallback (deg > 64)
    float m0 = -1e30f, m1 = -1e30f, m2 = -1e30f, m3 = -1e30f;
    for (int i = r0 + lane; i < r1; i += 64) {
      const float4 av = *(const float4*)&asad[(size_t)cs[i] * 8];
      m0 = fmaxf(m0, lrelu(av.x + adv.x)); m1 = fmaxf(m1, lrelu(av.y + adv.y));
      m2 = fmaxf(m2, lrelu(av.z + adv.z)); m3 = fmaxf(m3, lrelu(av.w + adv.w));
    }
#pragma unroll
    for (int d = 1; d < 64; d <<= 1) {
      m0 = fmaxf(m0, __shfl_xor(m0, d)); m1 = fmaxf(m1, __shfl_xor(m1, d));
      m2 = fmaxf(m2, __shfl_xor(m2, d)); m3 = fmaxf(m3, __shfl_xor(m3, d));
    }
    float d0 = 0.f, d1 = 0.f, d2 = 0.f, d3 = 0.f;
    for (int i = r0 + lane; i < r1; i += 64) {
      const float4 av = *(const float4*)&asad[(size_t)cs[i] * 8];
      d0 += __expf(lrelu(av.x + adv.x) - m0); d1 += __expf(lrelu(av.y + adv.y) - m1);
      d2 += __expf(lrelu(av.z + adv.z) - m2); d3 += __expf(lrelu(av.w + adv.w) - m3);
    }
#pragma unroll
    for (int d = 1; d < 64; d <<= 1) {
      d0 += __shfl_xor(d0, d); d1 += __shfl_xor(d1, d);
      d2 += __shfl_xor(d2, d); d3 += __shfl_xor(d3, d);
    }
    const float i0 = 1.f / (d0 + 1e-16f), i1 = 1.f / (d1 + 1e-16f);
    const float i2 = 1.f / (d2 + 1e-16f), i3 = 1.f / (d3 + 1e-16f);
    for (int base = r0; base < r1; base += 64) {
      const int ne = min(64, r1 - base);
      if (lane < ne) {
        const int s = cs[base + lane];
        const float4 av = *(const float4*)&asad[(size_t)s * 8];
        sb[wv][lane] = s * (K * 2);
        wl[wv][lane] = make_float4(__expf(lrelu(av.x + adv.x) - m0) * i0,
                                   __expf(lrelu(av.y + adv.y) - m1) * i1,
                                   __expf(lrelu(av.z + adv.z) - m2) * i2,
                                   __expf(lrelu(av.w + adv.w) - m3) * i3);
      }
      __builtin_amdgcn_wave_barrier();
      for (int g = 0; g < ne; ++g)
        edge_fma(fb + (size_t)sb[wv][g] + loff, wl[wv][g]);
      __builtin_amdgcn_wave_barrier();
    }
  }

#pragma unroll
  for (int j = 0; j < 4; ++j) {
    if (KC == 4) {
      uint2 ov;
      ov.x = pack2bf(acc[j][0], acc[j][1]);
      ov.y = pack2bf(acc[j][2], acc[j][3]);
      *(uint2*)&agg[(size_t)n * (4 * K) + j * K + lane * 4] = ov;
    } else {
      *(uint32_t*)&agg[(size_t)n * (4 * K) + j * K + lane * 2] = pack2bf(acc[j][0], acc[j][1]);
    }
  }
}

// ---------------- input-space GAT aggregation, H=1 (K=128): 2 nodes/block ------------

__global__ __launch_bounds__(128) void gat_agg_in1(const bf16_t* __restrict__ f,
                                                   const float* __restrict__ asad,
                                                   const int* __restrict__ rp,
                                                   const int* __restrict__ cs,
                                                   bf16_t* __restrict__ agg) {
  const int wv = threadIdx.x >> 6, lane = threadIdx.x & 63;
  const int n = blockIdx.x * 2 + wv;
  __shared__ int sb[2][64];
  __shared__ float wl[2][64];

  const int r0 = rp[n], r1 = rp[n + 1];
  const int deg = r1 - r0;
  const float adv = asad[(size_t)n * 2 + 1];
  const char* fb = (const char*)f;
  const size_t loff = (size_t)lane * 4;
  float a0 = 0.f, a1 = 0.f;

  auto fma2 = [&](uint32_t v, float w) { a0 += w * bflo(v); a1 += w * bfhi(v); };

  if (deg <= 64) {
    const bool valid = lane < deg;
    int s = 0;
    float e = -1e30f;
    if (valid) { s = cs[r0 + lane]; e = lrelu(asad[(size_t)s * 2] + adv); }
    float m = e;
#pragma unroll
    for (int d = 1; d < 64; d <<= 1) m = fmaxf(m, __shfl_xor(m, d));
    float x = valid ? __expf(e - m) : 0.f;
    float den = x;
#pragma unroll
    for (int d = 1; d < 64; d <<= 1) den += __shfl_xor(den, d);
    if (valid) { sb[wv][lane] = s * 256; wl[wv][lane] = x / (den + 1e-16f); }
    __builtin_amdgcn_wave_barrier();
    int g = 0;
    for (; g + 8 <= deg; g += 8) {
      uint32_t b[8];
      float w[8];
#pragma unroll
      for (int k = 0; k < 8; ++k) {
        b[k] = *(const uint32_t*)(fb + (size_t)sb[wv][g + k] + loff);
        w[k] = wl[wv][g + k];
      }
#pragma unroll
      for (int k = 0; k < 8; ++k) { a0 += w[k] * bflo(b[k]); a1 += w[k] * bfhi(b[k]); }
    }
    for (; g < deg; ++g)
      fma2(*(const uint32_t*)(fb + (size_t)sb[wv][g] + loff), wl[wv][g]);
  } else {
    float m = -1e30f;
    for (int i = r0 + lane; i < r1; i += 64) m = fmaxf(m, lrelu(asad[(size_t)cs[i] * 2] + adv));
#pragma unroll
    for (int d = 1; d < 64; d <<= 1) m = fmaxf(m, __shfl_xor(m, d));
    float den = 0.f;
    for (int i = r0 + lane; i < r1; i += 64) den += __expf(lrelu(asad[(size_t)cs[i] * 2] + adv) - m);
#pragma unroll
    for (int d = 1; d < 64; d <<= 1) den += __shfl_xor(den, d);
    const float dinv = 1.f / (den + 1e-16f);
    for (int base = r0; base < r1; base += 64) {
      const int ne = min(64, r1 - base);
      if (lane < ne) {
        const int s = cs[base + lane];
        sb[wv][lane] = s * 256;
        wl[wv][lane] = __expf(lrelu(asad[(size_t)s * 2] + adv) - m) * dinv;
      }
      __builtin_amdgcn_wave_barrier();
      for (int g = 0; g < ne; ++g)
        fma2(*(const uint32_t*)(fb + (size_t)sb[wv][g] + loff), wl[wv][g]);
      __builtin_amdgcn_wave_barrier();
    }
  }
  *(uint32_t*)&agg[(size_t)n * 128 + lane * 2] = pack2bf(a0, a1);
}

// ---------------- fused classifier tail ----------------

__global__ __launch_bounds__(256) void mlp_tail(const bf16_t* __restrict__ A,
                                                const bf16_t* __restrict__ M3t,
                                                const float* __restrict__ bm,
                                                const bf16_t* __restrict__ l2t,
                                                const float* __restrict__ l2b,
                                                const bf16_t* __restrict__ l3t,
                                                const float* __restrict__ l3b,
                                                float* __restrict__ out, int M) {
  __shared__ __align__(16) bf16_t As[128 * 128];
  __shared__ __align__(16) bf16_t Ws[128 * 128];
  const int t = threadIdx.x, wave = t >> 6, lane = t & 63;
  const int ln15 = lane & 15, quad = lane >> 4;
  const int bmr = blockIdx.x * 128;
  const int rowLim = M - 1 - bmr;

#pragma unroll
  for (int r = 0; r < 8; ++r) {
    int base = (wave * 8 + r) * 1024;
    int flat = base + lane * 16;
    int row = flat >> 8;
    int grow = row < rowLim ? row : rowLim;
    const char* gp = (const char*)A + (size_t)grow * 256 + (flat & 255);
    __builtin_amdgcn_global_load_lds((const AS1 void*)gp,
                                     (AS3 void*)((char*)As + base), 16, 0, 0);
  }
#pragma unroll
  for (int r = 0; r < 8; ++r) {
    int base = (wave * 8 + r) * 1024;
    __builtin_amdgcn_global_load_lds((const AS1 void*)((const char*)M3t + base + lane * 16),
                                     (AS3 void*)((char*)Ws + base), 16, 0, 0);
  }
  __syncthreads();

  const int wm = wave * 32;
  f32x4 a1[2][8];
#pragma unroll
  for (int mi = 0; mi < 2; ++mi)
#pragma unroll
    for (int ni = 0; ni < 8; ++ni) a1[mi][ni] = (f32x4){0.f, 0.f, 0.f, 0.f};
#pragma unroll
  for (int kk = 0; kk < 128; kk += 32) {
    bf16x8 af[2];
#pragma unroll
    for (int mi = 0; mi < 2; ++mi)
      af[mi] = *(const bf16x8*)&As[(wm + mi * 16 + ln15) * 128 + kk + quad * 8];
#pragma unroll
    for (int ni = 0; ni < 8; ++ni) {
      bf16x8 bf = *(const bf16x8*)&Ws[(ni * 16 + ln15) * 128 + kk + quad * 8];
#pragma unroll
      for (int mi = 0; mi < 2; ++mi)
        a1[mi][ni] = __builtin_amdgcn_mfma_f32_16x16x32_bf16(af[mi], bf, a1[mi][ni], 0, 0, 0);
    }
  }
  __syncthreads();

#pragma unroll
  for (int r = 0; r < 4; ++r) {
    int base = (wave * 4 + r) * 1024;
    __builtin_amdgcn_global_load_lds((const AS1 void*)((const char*)l2t + base + lane * 16),
                                     (AS3 void*)((char*)Ws + base), 16, 0, 0);
  }
#pragma unroll
  for (int r = 0; r < 2; ++r) {
    int base = (wave * 2 + r) * 1024;
    __builtin_amdgcn_global_load_lds((const AS1 void*)((const char*)l3t + base + lane * 16),
                                     (AS3 void*)((char*)Ws + 8192 * 2 + base), 16, 0, 0);
  }
#pragma unroll
  for (int mi = 0; mi < 2; ++mi) {
    int r0 = wm + mi * 16 + quad * 4;
#pragma unroll
    for (int ni = 0; ni < 8; ++ni) {
      int c = ni * 16 + ln15;
      float bv = bm[c];
#pragma unroll
      for (int reg = 0; reg < 4; ++reg)
        As[(r0 + reg) * 128 + c] = (bf16_t)fmaxf(a1[mi][ni][reg] + bv, 0.f);
    }
  }
  __syncthreads();

  f32x4 a2[2][4];
#pragma unroll
  for (int mi = 0; mi < 2; ++mi)
#pragma unroll
    for (int ni = 0; ni < 4; ++ni) a2[mi][ni] = (f32x4){0.f, 0.f, 0.f, 0.f};
#pragma unroll
  for (int kk = 0; kk < 128; kk += 32) {
    bf16x8 af[2];
#pragma unroll
    for (int mi = 0; mi < 2; ++mi)
      af[mi] = *(const bf16x8*)&As[(wm + mi * 16 + ln15) * 128 + kk + quad * 8];
#pragma unroll
    for (int ni = 0; ni < 4; ++ni) {
      bf16x8 bf = *(const bf16x8*)&Ws[(ni * 16 + ln15) * 128 + kk + quad * 8];
#pragma unroll
      for (int mi = 0; mi < 2; ++mi)
        a2[mi][ni] = __builtin_amdgcn_mfma_f32_16x16x32_bf16(af[mi], bf, a2[mi][ni], 0, 0, 0);
    }
  }
  __syncthreads();

#pragma unroll
  for (int mi = 0; mi < 2; ++mi) {
    int r0 = wm + mi * 16 + quad * 4;
#pragma unroll
    for (int ni = 0; ni < 4; ++ni) {
      int c = ni * 16 + ln15;
      float bv = l2b[c];
#pragma unroll
      for (int reg = 0; reg < 4; ++reg)
        As[(r0 + reg) * 64 + c] = (bf16_t)fmaxf(a2[mi][ni][reg] + bv, 0.f);
    }
  }
  __syncthreads();

  f32x4 a3[2][4];
#pragma unroll
  for (int mi = 0; mi < 2; ++mi)
#pragma unroll
    for (int ni = 0; ni < 4; ++ni) a3[mi][ni] = (f32x4){0.f, 0.f, 0.f, 0.f};
#pragma unroll
  for (int kk = 0; kk < 64; kk += 32) {
    bf16x8 af[2];
#pragma unroll
    for (int mi = 0; mi < 2; ++mi)
      af[mi] = *(const bf16x8*)&As[(wm + mi * 16 + ln15) * 64 + kk + quad * 8];
#pragma unroll
    for (int ni = 0; ni < 4; ++ni) {
      bf16x8 bf = *(const bf16x8*)&Ws[8192 + (ni * 16 + ln15) * 64 + kk + quad * 8];
#pragma unroll
      for (int mi = 0; mi < 2; ++mi)
        a3[mi][ni] = __builtin_amdgcn_mfma_f32_16x16x32_bf16(af[mi], bf, a3[mi][ni], 0, 0, 0);
    }
  }
#pragma unroll
  for (int mi = 0; mi < 2; ++mi) {
    int r0 = wm + mi * 16 + quad * 4;
#pragma unroll
    for (int ni = 0; ni < 4; ++ni) {
      int c = ni * 16 + ln15;
      float bv = l3b[c];
#pragma unroll
      for (int reg = 0; reg < 4; ++reg) {
        int r = bmr + r0 + reg;
        if (r < M) {
          float v = a3[mi][ni][reg] + bv;
          out[(size_t)r * 64 + c] = 1.f / (1.f + __expf(-v));
        }
      }
    }
  }
}

// ---------------- launch ----------------

extern "C" void kernel_launch(void* const* d_in, const int* in_sizes, int n_in,
                              void* d_out, int out_size, void* d_ws, size_t ws_size,
                              hipStream_t stream) {
  const float* x      = (const float*)d_in[0];
  const int*   ei     = (const int*)d_in[1];
  const float* W1     = (const float*)d_in[2];
  const float* a_src1 = (const float*)d_in[3];
  const float* a_dst1 = (const float*)d_in[4];
  const float* b1     = (const float*)d_in[5];
  const float* W2     = (const float*)d_in[6];
  const float* a_src2 = (const float*)d_in[7];
  const float* a_dst2 = (const float*)d_in[8];
  const float* b2     = (const float*)d_in[9];
  const float* W3     = (const float*)d_in[10];
  const float* a_src3 = (const float*)d_in[11];
  const float* a_dst3 = (const float*)d_in[12];
  const float* b3     = (const float*)d_in[13];
  const float* bn1g = (const float*)d_in[14];
  const float* bn1b = (const float*)d_in[15];
  const float* bn1m = (const float*)d_in[16];
  const float* bn1v = (const float*)d_in[17];
  const float* bn2g = (const float*)d_in[18];
  const float* bn2b = (const float*)d_in[19];
  const float* bn2m = (const float*)d_in[20];
  const float* bn2v = (const float*)d_in[21];
  const float* l1w = (const float*)d_in[22];
  const float* l1b = (const float*)d_in[23];
  const float* l2w = (const float*)d_in[24];
  const float* l2b = (const float*)d_in[25];
  const float* l3w = (const float*)d_in[26];
  const float* l3b = (const float*)d_in[27];
  float* out = (float*)d_out;

  const int N = NN;
  const int E = in_sizes[1] / 2;
  const int ET = E + N;
  const int EB = (ET + 255) / 256;  // hist/scatter blocks

  char* p = (char*)d_ws;
  auto carve = [&](size_t bytes) {
    char* q = p;
    p += (bytes + 255) & ~(size_t)255;
    return q;
  };
  bf16_t* xb    = (bf16_t*)carve((size_t)N * 256 * 2);
  bf16_t* aggb  = (bf16_t*)carve((size_t)N * 1024 * 2);
  bf16_t* f1b   = (bf16_t*)carve((size_t)N * 128 * 2);
  bf16_t* f2b   = (bf16_t*)carve((size_t)N * 128 * 2);
  float* asadA  = (float*)carve((size_t)N * 8 * 4);
  float* asadBC = (float*)carve((size_t)N * 10 * 4);  // B: N*8, C: N*2 (contiguous for zeroing)
  int* cnt      = (int*)carve((size_t)N * 4);
  int* cursor   = (int*)carve((size_t)N * 4);
  int* row_ptr  = (int*)carve((size_t)(N + 1) * 4);
  int* col      = (int*)carve((size_t)ET * 4);
  bf16_t* Ws1t  = (bf16_t*)carve((size_t)128 * 1024 * 2);
  bf16_t* Ws2t  = (bf16_t*)carve((size_t)128 * 512 * 2);
  bf16_t* M3t   = (bf16_t*)carve((size_t)128 * 128 * 2);
  bf16_t* l2t   = (bf16_t*)carve((size_t)64 * 128 * 2);
  bf16_t* l3t   = (bf16_t*)carve((size_t)64 * 64 * 2);
  float* P1     = (float*)carve((size_t)8 * 256 * 4);
  float* P2     = (float*)carve((size_t)8 * 128 * 4);
  float* P3     = (float*)carve((size_t)2 * 128 * 4);
  float* bm     = (float*)carve((size_t)128 * 4);
  (void)ws_size; (void)n_in; (void)out_size;

  float* asadB = asadBC;
  float* asadC = asadBC + (size_t)N * 8;

  hipMemsetAsync(cnt, 0, (size_t)N * 4, stream);

  // --- prep mega-kernel: wprep | alpha_proj | merge_w3l1 | hist | zero asadB/C ---
  Prep1Args pa;
  pa.wp.d[0] = {W1,  Ws1t, 256, 128, 4, 0.25f, 0};
  pa.wp.d[1] = {W2,  Ws2t, 128, 128, 4, 0.25f, 128};
  pa.wp.d[2] = {l2w, l2t,  128, 64,  1, 1.0f,  192};
  pa.wp.d[3] = {l3w, l3t,  64,  64,  1, 1.0f,  200};
  pa.W1 = W1; pa.as1 = a_src1; pa.ad1 = a_dst1;
  pa.W2 = W2; pa.as2 = a_src2; pa.ad2 = a_dst2;
  pa.W3 = W3; pa.as3 = a_src3; pa.ad3 = a_dst3;
  pa.P1 = P1; pa.P2 = P2; pa.P3 = P3;
  pa.W3m = W3; pa.L1w = l1w; pa.b3v = b3; pa.l1b = l1b;
  pa.M3t = M3t; pa.bm = bm;
  pa.ei = ei; pa.E = E; pa.N = N; pa.EB = EB;
  pa.cnt = cnt;
  pa.zbuf = asadBC; pa.zcount = (N * 10 * 4) / 16;  // float4 count
  const int zb = (pa.zcount + 255) / 256;
  prep1<<<780 + EB + zb, 256, 0, stream>>>(pa);

  scan_kernel<<<1, 1024, 0, stream>>>(cnt, row_ptr, cursor, N);
  scatter_cast<<<EB + N / 4, 256, 0, stream>>>(ei, E, N, EB, cursor, col, x, P1, xb, asadA);

  const int gm = (N + 127) / 128;  // 157
  const int gb = N / 2;            // 10000 gather blocks (2 nodes each)

  // --- GAT layer 1 ---
  gat_agg_in4<256><<<gb, 128, 0, stream>>>(xb, asadA, row_ptr, col, aggb);
  gemm_mfma<64, 3, 8, bf16_t><<<dim3(gm, 2), 256, 0, stream>>>(
      aggb, Ws1t, b1, bn1g, bn1b, bn1m, bn1v, P2, asadB, f1b, N, 128, 1024);

  // --- GAT layer 2 ---
  gat_agg_in4<128><<<gb, 128, 0, stream>>>(f1b, asadB, row_ptr, col, aggb);
  gemm_mfma<64, 3, 2, bf16_t><<<dim3(gm, 2), 256, 0, stream>>>(
      aggb, Ws2t, b2, bn2g, bn2b, bn2m, bn2v, P3, asadC, f2b, N, 128, 512);

  // --- GAT layer 3 (H=1) + fused classifier tail ---
  gat_agg_in1<<<gb, 128, 0, stream>>>(f2b, asadC, row_ptr, col, aggb);
  mlp_tail<<<gm, 256, 0, stream>>>(aggb, M3t, bm, l2t, l2b, l3t, l3b, out, N);
}

// Round 9
// 339.643 us; speedup vs baseline: 1.1748x; 1.0042x over previous
//
#include <hip/hip_runtime.h>
#include <cstdint>
#include <cstddef>

#define NN 20000

typedef __bf16 bf16_t;
typedef __bf16 bf16x8 __attribute__((ext_vector_type(8)));
typedef float f32x4 __attribute__((ext_vector_type(4)));

#define AS1 __attribute__((address_space(1)))
#define AS3 __attribute__((address_space(3)))

__device__ __forceinline__ float lrelu(float x) { return x >= 0.f ? x : 0.2f * x; }
__device__ __forceinline__ float bflo(uint32_t u) { return __uint_as_float(u << 16); }
__device__ __forceinline__ float bfhi(uint32_t u) { return __uint_as_float(u & 0xffff0000u); }

__device__ __forceinline__ uint32_t pack2bf(float a, float b) {
  bf16_t x = (bf16_t)a, y = (bf16_t)b;
  uint16_t ux = __builtin_bit_cast(uint16_t, x);
  uint16_t uy = __builtin_bit_cast(uint16_t, y);
  return (uint32_t)ux | ((uint32_t)uy << 16);
}

// ---------------- CSR scan ----------------

__global__ __launch_bounds__(1024) void scan_kernel(const int* __restrict__ cnt,
                                                    int* __restrict__ row_ptr,
                                                    int* __restrict__ cursor, int n) {
  __shared__ int wsum[16];
  const int t = threadIdx.x;
  const int lane = t & 63, w = t >> 6;
  int carry = 0;
  for (int base = 0; base < n; base += 1024) {
    int i = base + t;
    int v = (i < n) ? cnt[i] : 0;
    int x = v;
#pragma unroll
    for (int d = 1; d < 64; d <<= 1) {
      int y = __shfl_up(x, d);
      if (lane >= d) x += y;
    }
    if (lane == 63) wsum[w] = x;
    __syncthreads();
    if (t < 16) {
      int s = wsum[t];
#pragma unroll
      for (int d = 1; d < 16; d <<= 1) {
        int y = __shfl_up(s, d);
        if (t >= d) s += y;
      }
      wsum[t] = s;
    }
    __syncthreads();
    int blocksum = wsum[15];
    int wprefix = (w == 0) ? 0 : wsum[w - 1];
    int excl = carry + wprefix + (x - v);
    if (i < n) { row_ptr[i] = excl; cursor[i] = excl; }
    carry += blocksum;
    __syncthreads();
  }
  if (t == 0) row_ptr[n] = carry;
}

// ---------------- prep mega-kernel ----------------
// block ranges: [0,204) wprep | [204,716) alpha_proj | [716,780) merge_w3l1 | [780,780+EB) hist

struct WDesc { const float* W; bf16_t* Bt; int K; int Cw; int H; float scale; int b0; };
struct WPack { WDesc d[4]; };

struct Prep1Args {
  WPack wp;
  const float *W1, *as1, *ad1, *W2, *as2, *ad2, *W3, *as3, *ad3;
  float *P1, *P2, *P3;
  const float *W3m, *L1w, *b3v, *l1b;
  bf16_t* M3t; float* bm;
  const int* ei; int E, N, EB;
  int* cnt;
};

__global__ __launch_bounds__(256) void prep1(Prep1Args a) {
  __shared__ float tile[32][33];
  const int b = blockIdx.x;
  const int t = threadIdx.x;

  if (b < 204) {
    int i = 3;
#pragma unroll
    for (int k = 2; k >= 0; --k)
      if (b < a.wp.d[k + 1].b0) i = k;
    const WDesc de = a.wp.d[i];
    const int bi = b - de.b0;
    const int ktiles = de.K / 32;
    const int kt = bi % ktiles, rt = bi / ktiles;
    const int gc = rt * 32;
    const int h = gc / de.Cw, c0 = gc % de.Cw;
    const int tx = t & 31, ty = t >> 5;
#pragma unroll
    for (int r = 0; r < 32; r += 8)
      tile[ty + r][tx] = de.W[(size_t)(kt * 32 + ty + r) * (de.H * de.Cw) + h * de.Cw + c0 + tx];
    __syncthreads();
#pragma unroll
    for (int r = 0; r < 32; r += 8)
      de.Bt[(size_t)(c0 + ty + r) * (de.H * de.K) + h * de.K + kt * 32 + tx] =
          (bf16_t)(de.scale * tile[tx][ty + r]);
  } else if (b < 716) {
    const int kk = b - 204;
    const float *W, *asrc, *adst;
    float* P;
    int K, H, k;
    if (kk < 256)      { W = a.W1; asrc = a.as1; adst = a.ad1; P = a.P1; K = 256; H = 4; k = kk; }
    else if (kk < 384) { W = a.W2; asrc = a.as2; adst = a.ad2; P = a.P2; K = 128; H = 4; k = kk - 256; }
    else               { W = a.W3; asrc = a.as3; adst = a.ad3; P = a.P3; K = 128; H = 1; k = kk - 384; }
    for (int j = 0; j < 2 * H; ++j) {
      const int h = (j < H) ? j : j - H;
      const float* av = (j < H) ? asrc : adst;
      float pv = 0.f;
      if (t < 128) pv = W[(size_t)k * (H * 128) + h * 128 + t] * av[h * 128 + t];
#pragma unroll
      for (int d = 1; d < 64; d <<= 1) pv += __shfl_xor(pv, d);
      if (t == 0 || t == 64) tile[0][t >> 6] = pv;
      __syncthreads();
      if (t == 0) P[j * K + k] = tile[0][0] + tile[0][1];
      __syncthreads();
    }
  } else if (b < 780) {
    const int idx = (b - 716) * 256 + t;
    const int k = idx >> 7, c = idx & 127;
    float s = 0.f;
    for (int m = 0; m < 128; ++m) s += a.W3m[k * 128 + m] * a.L1w[m * 128 + c];
    a.M3t[c * 128 + k] = (bf16_t)s;
    if (k == 0) {
      float tt = a.l1b[c];
      for (int m = 0; m < 128; ++m) tt += a.b3v[m] * a.L1w[m * 128 + c];
      a.bm[c] = tt;
    }
  } else {
    const int i = (b - 780) * 256 + t;
    if (i < a.E + a.N) {
      int dst = (i < a.E) ? a.ei[a.E + i] : (i - a.E);
      atomicAdd(&a.cnt[dst], 1);
    }
  }
}

// ---------------- scatter + fused cast+layer1-alpha ----------------

__global__ __launch_bounds__(256) void scatter_cast(const int* __restrict__ ei, int E, int N,
                                                    int EB, int* __restrict__ cursor,
                                                    int* __restrict__ col,
                                                    const float* __restrict__ x,
                                                    const float* __restrict__ P1,
                                                    bf16_t* __restrict__ xb,
                                                    float* __restrict__ asadA) {
  const int b = blockIdx.x, t = threadIdx.x;
  if (b < EB) {
    const int i = b * 256 + t;
    if (i < E + N) {
      int src, dst;
      if (i < E) { src = ei[i]; dst = ei[E + i]; }
      else       { src = i - E; dst = src; }
      int slot = atomicAdd(&cursor[dst], 1);
      col[slot] = src;
    }
  } else {
    const int wv = t >> 6, lane = t & 63;
    const int n = (b - EB) * 4 + wv;
    const float4 v = *(const float4*)&x[(size_t)n * 256 + lane * 4];
    uint2 ov;
    ov.x = pack2bf(v.x, v.y);
    ov.y = pack2bf(v.z, v.w);
    *(uint2*)&xb[(size_t)n * 256 + lane * 4] = ov;
    float s[8];
#pragma unroll
    for (int j = 0; j < 8; ++j) {
      const float4 pj = *(const float4*)&P1[j * 256 + lane * 4];
      s[j] = v.x * pj.x + v.y * pj.y + v.z * pj.z + v.w * pj.w;
    }
#pragma unroll
    for (int j = 0; j < 8; ++j)
#pragma unroll
      for (int d = 1; d < 64; d <<= 1) s[j] += __shfl_xor(s[j], d);
    if (lane == 0) {
#pragma unroll
      for (int j = 0; j < 8; ++j) asadA[(size_t)n * 8 + j] = s[j];
    }
  }
}

// ---------------- bf16 MFMA GEMM: C = act(A @ Bt^T + bias) ----------------
// ACT: 1=relu, 3=BN(eval)+relu

template <int TN, int ACT, typename OUT_T>
__global__ __launch_bounds__(256) void gemm_mfma(const bf16_t* __restrict__ A,
                                                 const bf16_t* __restrict__ Bt,
                                                 const float* __restrict__ bias,
                                                 const float* __restrict__ bng,
                                                 const float* __restrict__ bnb,
                                                 const float* __restrict__ bnm,
                                                 const float* __restrict__ bnv,
                                                 OUT_T* __restrict__ C,
                                                 int M, int N, int K) {
  constexpr int TM = 128, BK = 64;
  constexpr int MT = (TN == 128) ? 4 : 2;
  constexpr int NRB = (TN * BK * 2) / 4096;
  __shared__ __align__(16) bf16_t As[TM * BK];
  __shared__ __align__(16) bf16_t Bs[TN * BK];

  const int t = threadIdx.x;
  const int wave = t >> 6, lane = t & 63;
  const int ln15 = lane & 15, quad = lane >> 4;
  const int bm = blockIdx.x * TM;
  const int bn = blockIdx.y * TN;
  const int wm = (TN == 128) ? (wave >> 1) * 64 : wave * 32;
  const int wn = (TN == 128) ? (wave & 1) * 64 : 0;
  const int rowLimA = M - 1 - bm;
  const size_t strideAB = (size_t)K * 2;

  f32x4 acc[MT][4];
#pragma unroll
  for (int mi = 0; mi < MT; ++mi)
#pragma unroll
    for (int ni = 0; ni < 4; ++ni) acc[mi][ni] = (f32x4){0.f, 0.f, 0.f, 0.f};

  const char* gA = (const char*)(A + (size_t)bm * K);
  const char* gB = (const char*)(Bt + (size_t)bn * K);

  for (int k0 = 0; k0 < K; k0 += BK) {
#pragma unroll
    for (int r = 0; r < 4; ++r) {
      int base = (wave * 4 + r) * 1024;
      int flat = base + lane * 16;
      int row = flat >> 7;
      int grow = row < rowLimA ? row : rowLimA;
      const char* gp = gA + (size_t)grow * strideAB + (size_t)(k0 * 2) + (flat & 127);
      __builtin_amdgcn_global_load_lds((const AS1 void*)gp,
                                       (AS3 void*)((char*)As + base), 16, 0, 0);
    }
#pragma unroll
    for (int r = 0; r < NRB; ++r) {
      int base = (wave * NRB + r) * 1024;
      int flat = base + lane * 16;
      int row = flat >> 7;
      const char* gp = gB + (size_t)row * strideAB + (size_t)(k0 * 2) + (flat & 127);
      __builtin_amdgcn_global_load_lds((const AS1 void*)gp,
                                       (AS3 void*)((char*)Bs + base), 16, 0, 0);
    }
    __syncthreads();
#pragma unroll
    for (int kk = 0; kk < BK; kk += 32) {
      bf16x8 af[MT], bfr[4];
#pragma unroll
      for (int mi = 0; mi < MT; ++mi)
        af[mi] = *(const bf16x8*)&As[(wm + mi * 16 + ln15) * BK + kk + quad * 8];
#pragma unroll
      for (int ni = 0; ni < 4; ++ni)
        bfr[ni] = *(const bf16x8*)&Bs[(wn + ni * 16 + ln15) * BK + kk + quad * 8];
#pragma unroll
      for (int mi = 0; mi < MT; ++mi)
#pragma unroll
        for (int ni = 0; ni < 4; ++ni)
          acc[mi][ni] = __builtin_amdgcn_mfma_f32_16x16x32_bf16(af[mi], bfr[ni], acc[mi][ni], 0, 0, 0);
    }
    __syncthreads();
  }

#pragma unroll
  for (int mi = 0; mi < MT; ++mi) {
    int r0 = bm + wm + mi * 16 + quad * 4;
#pragma unroll
    for (int ni = 0; ni < 4; ++ni) {
      int c = bn + wn + ni * 16 + ln15;
      float bv = bias ? bias[c] : 0.f;
      float sc = 1.f, sh = 0.f;
      if (ACT == 3) {
        sc = bng[c] * rsqrtf(bnv[c] + 1e-5f);
        sh = bnb[c] - bnm[c] * sc;
      }
#pragma unroll
      for (int reg = 0; reg < 4; ++reg) {
        int r = r0 + reg;
        if (r < M) {
          float v = acc[mi][ni][reg] + bv;
          if (ACT == 1) v = fmaxf(v, 0.f);
          else if (ACT == 3) v = fmaxf(v * sc + sh, 0.f);
          C[(size_t)r * N + c] = (OUT_T)v;
        }
      }
    }
  }
}

// ---------------- alpha logits for layers 2/3: asad[n, j] = f[n,:] . P[j,:] ----------

template <int K, int H>
__global__ __launch_bounds__(256) void alpha_gemm(const bf16_t* __restrict__ f,
                                                  const float* __restrict__ P,
                                                  float* __restrict__ asad) {
  constexpr int J = 2 * H;
  constexpr int KC = K / 64;
  const int wv = threadIdx.x >> 6, lane = threadIdx.x & 63;
  const int n = blockIdx.x * 4 + wv;
  float v[KC];
  if (KC == 4) {
    uint2 pv = *(const uint2*)&f[(size_t)n * K + lane * 4];
    v[0] = bflo(pv.x); v[1] = bfhi(pv.x); v[2] = bflo(pv.y); v[3] = bfhi(pv.y);
  } else {
    uint32_t pv = *(const uint32_t*)&f[(size_t)n * K + lane * 2];
    v[0] = bflo(pv); v[1] = bfhi(pv);
  }
  float s[J];
#pragma unroll
  for (int j = 0; j < J; ++j) {
    float acc = 0.f;
#pragma unroll
    for (int q = 0; q < KC; ++q) acc += v[q] * P[j * K + lane * KC + q];
    s[j] = acc;
  }
#pragma unroll
  for (int j = 0; j < J; ++j)
#pragma unroll
    for (int d = 1; d < 64; d <<= 1) s[j] += __shfl_xor(s[j], d);
  if (lane == 0) {
#pragma unroll
    for (int j = 0; j < J; ++j) asad[(size_t)n * J + j] = s[j];
  }
}

// ---------------- input-space GAT aggregation, H=4: wave/node, 2 nodes/block ---------

template <int K>
__global__ __launch_bounds__(128) void gat_agg_in4(const bf16_t* __restrict__ f,
                                                   const float* __restrict__ asad,
                                                   const int* __restrict__ rp,
                                                   const int* __restrict__ cs,
                                                   bf16_t* __restrict__ agg) {
  constexpr int KC = K / 64;
  const int wv = threadIdx.x >> 6, lane = threadIdx.x & 63;
  const int n = blockIdx.x * 2 + wv;
  __shared__ int sb[2][64];
  __shared__ float4 wl[2][64];

  const int r0 = rp[n], r1 = rp[n + 1];
  const int deg = r1 - r0;
  const float4 adv = *(const float4*)&asad[(size_t)n * 8 + 4];
  const char* fb = (const char*)f;
  const size_t loff = (size_t)lane * (KC * 2);

  float acc[4][KC];
#pragma unroll
  for (int j = 0; j < 4; ++j)
#pragma unroll
    for (int q = 0; q < KC; ++q) acc[j][q] = 0.f;

  auto edge_fma = [&](const char* gp, float4 w4) {
    if (KC == 4) {
      uint2 b = *(const uint2*)gp;
      float v0 = bflo(b.x), v1 = bfhi(b.x), v2 = bflo(b.y), v3 = bfhi(b.y);
      acc[0][0] += w4.x * v0; acc[0][1] += w4.x * v1; acc[0][2] += w4.x * v2; acc[0][3] += w4.x * v3;
      acc[1][0] += w4.y * v0; acc[1][1] += w4.y * v1; acc[1][2] += w4.y * v2; acc[1][3] += w4.y * v3;
      acc[2][0] += w4.z * v0; acc[2][1] += w4.z * v1; acc[2][2] += w4.z * v2; acc[2][3] += w4.z * v3;
      acc[3][0] += w4.w * v0; acc[3][1] += w4.w * v1; acc[3][2] += w4.w * v2; acc[3][3] += w4.w * v3;
    } else {
      uint32_t b = *(const uint32_t*)gp;
      float v0 = bflo(b), v1 = bfhi(b);
      acc[0][0] += w4.x * v0; acc[0][1] += w4.x * v1;
      acc[1][0] += w4.y * v0; acc[1][1] += w4.y * v1;
      acc[2][0] += w4.z * v0; acc[2][1] += w4.z * v1;
      acc[3][0] += w4.w * v0; acc[3][1] += w4.w * v1;
    }
  };

  if (deg <= 64) {
    const bool valid = lane < deg;
    int s = 0;
    float e0 = -1e30f, e1 = -1e30f, e2 = -1e30f, e3 = -1e30f;
    if (valid) {
      s = cs[r0 + lane];
      const float4 av = *(const float4*)&asad[(size_t)s * 8];
      e0 = lrelu(av.x + adv.x); e1 = lrelu(av.y + adv.y);
      e2 = lrelu(av.z + adv.z); e3 = lrelu(av.w + adv.w);
    }
    float m0 = e0, m1 = e1, m2 = e2, m3 = e3;
#pragma unroll
    for (int d = 1; d < 64; d <<= 1) {
      m0 = fmaxf(m0, __shfl_xor(m0, d)); m1 = fmaxf(m1, __shfl_xor(m1, d));
      m2 = fmaxf(m2, __shfl_xor(m2, d)); m3 = fmaxf(m3, __shfl_xor(m3, d));
    }
    float x0 = valid ? __expf(e0 - m0) : 0.f;
    float x1 = valid ? __expf(e1 - m1) : 0.f;
    float x2 = valid ? __expf(e2 - m2) : 0.f;
    float x3 = valid ? __expf(e3 - m3) : 0.f;
    float d0 = x0, d1 = x1, d2 = x2, d3 = x3;
#pragma unroll
    for (int d = 1; d < 64; d <<= 1) {
      d0 += __shfl_xor(d0, d); d1 += __shfl_xor(d1, d);
      d2 += __shfl_xor(d2, d); d3 += __shfl_xor(d3, d);
    }
    if (valid) {
      sb[wv][lane] = s * (K * 2);
      wl[wv][lane] = make_float4(x0 / (d0 + 1e-16f), x1 / (d1 + 1e-16f),
                                 x2 / (d2 + 1e-16f), x3 / (d3 + 1e-16f));
    }
    __builtin_amdgcn_wave_barrier();

    int g = 0;
    for (; g + 8 <= deg; g += 8) {
      const char* p[8];
      float4 w[8];
#pragma unroll
      for (int k = 0; k < 8; ++k) { p[k] = fb + (size_t)sb[wv][g + k] + loff; w[k] = wl[wv][g + k]; }
      if (KC == 4) {
        uint2 b[8];
#pragma unroll
        for (int k = 0; k < 8; ++k) b[k] = *(const uint2*)p[k];
#pragma unroll
        for (int k = 0; k < 8; ++k) {
          float v0 = bflo(b[k].x), v1 = bfhi(b[k].x), v2 = bflo(b[k].y), v3 = bfhi(b[k].y);
          acc[0][0] += w[k].x * v0; acc[0][1] += w[k].x * v1; acc[0][2] += w[k].x * v2; acc[0][3] += w[k].x * v3;
          acc[1][0] += w[k].y * v0; acc[1][1] += w[k].y * v1; acc[1][2] += w[k].y * v2; acc[1][3] += w[k].y * v3;
          acc[2][0] += w[k].z * v0; acc[2][1] += w[k].z * v1; acc[2][2] += w[k].z * v2; acc[2][3] += w[k].z * v3;
          acc[3][0] += w[k].w * v0; acc[3][1] += w[k].w * v1; acc[3][2] += w[k].w * v2; acc[3][3] += w[k].w * v3;
        }
      } else {
        uint32_t b[8];
#pragma unroll
        for (int k = 0; k < 8; ++k) b[k] = *(const uint32_t*)p[k];
#pragma unroll
        for (int k = 0; k < 8; ++k) {
          float v0 = bflo(b[k]), v1 = bfhi(b[k]);
          acc[0][0] += w[k].x * v0; acc[0][1] += w[k].x * v1;
          acc[1][0] += w[k].y * v0; acc[1][1] += w[k].y * v1;
          acc[2][0] += w[k].z * v0; acc[2][1] += w[k].z * v1;
          acc[3][0] += w[k].w * v0; acc[3][1] += w[k].w * v1;
        }
      }
    }
    for (; g < deg; ++g)
      edge_fma(fb + (size_t)sb[wv][g] + loff, wl[wv][g]);
  } else {
    float m0 = -1e30f, m1 = -1e30f, m2 = -1e30f, m3 = -1e30f;
    for (int i = r0 + lane; i < r1; i += 64) {
      const float4 av = *(const float4*)&asad[(size_t)cs[i] * 8];
      m0 = fmaxf(m0, lrelu(av.x + adv.x)); m1 = fmaxf(m1, lrelu(av.y + adv.y));
      m2 = fmaxf(m2, lrelu(av.z + adv.z)); m3 = fmaxf(m3, lrelu(av.w + adv.w));
    }
#pragma unroll
    for (int d = 1; d < 64; d <<= 1) {
      m0 = fmaxf(m0, __shfl_xor(m0, d)); m1 = fmaxf(m1, __shfl_xor(m1, d));
      m2 = fmaxf(m2, __shfl_xor(m2, d)); m3 = fmaxf(m3, __shfl_xor(m3, d));
    }
    float d0 = 0.f, d1 = 0.f, d2 = 0.f, d3 = 0.f;
    for (int i = r0 + lane; i < r1; i += 64) {
      const float4 av = *(const float4*)&asad[(size_t)cs[i] * 8];
      d0 += __expf(lrelu(av.x + adv.x) - m0); d1 += __expf(lrelu(av.y + adv.y) - m1);
      d2 += __expf(lrelu(av.z + adv.z) - m2); d3 += __expf(lrelu(av.w + adv.w) - m3);
    }
#pragma unroll
    for (int d = 1; d < 64; d <<= 1) {
      d0 += __shfl_xor(d0, d); d1 += __shfl_xor(d1, d);
      d2 += __shfl_xor(d2, d); d3 += __shfl_xor(d3, d);
    }
    const float i0 = 1.f / (d0 + 1e-16f), i1 = 1.f / (d1 + 1e-16f);
    const float i2 = 1.f / (d2 + 1e-16f), i3 = 1.f / (d3 + 1e-16f);
    for (int base = r0; base < r1; base += 64) {
      const int ne = min(64, r1 - base);
      if (lane < ne) {
        const int s = cs[base + lane];
        const float4 av = *(const float4*)&asad[(size_t)s * 8];
        sb[wv][lane] = s * (K * 2);
        wl[wv][lane] = make_float4(__expf(lrelu(av.x + adv.x) - m0) * i0,
                                   __expf(lrelu(av.y + adv.y) - m1) * i1,
                                   __expf(lrelu(av.z + adv.z) - m2) * i2,
                                   __expf(lrelu(av.w + adv.w) - m3) * i3);
      }
      __builtin_amdgcn_wave_barrier();
      for (int g = 0; g < ne; ++g)
        edge_fma(fb + (size_t)sb[wv][g] + loff, wl[wv][g]);
      __builtin_amdgcn_wave_barrier();
    }
  }

#pragma unroll
  for (int j = 0; j < 4; ++j) {
    if (KC == 4) {
      uint2 ov;
      ov.x = pack2bf(acc[j][0], acc[j][1]);
      ov.y = pack2bf(acc[j][2], acc[j][3]);
      *(uint2*)&agg[(size_t)n * (4 * K) + j * K + lane * 4] = ov;
    } else {
      *(uint32_t*)&agg[(size_t)n * (4 * K) + j * K + lane * 2] = pack2bf(acc[j][0], acc[j][1]);
    }
  }
}

// ---------------- input-space GAT aggregation, H=1 (K=128): 2 nodes/block ------------

__global__ __launch_bounds__(128) void gat_agg_in1(const bf16_t* __restrict__ f,
                                                   const float* __restrict__ asad,
                                                   const int* __restrict__ rp,
                                                   const int* __restrict__ cs,
                                                   bf16_t* __restrict__ agg) {
  const int wv = threadIdx.x >> 6, lane = threadIdx.x & 63;
  const int n = blockIdx.x * 2 + wv;
  __shared__ int sb[2][64];
  __shared__ float wl[2][64];

  const int r0 = rp[n], r1 = rp[n + 1];
  const int deg = r1 - r0;
  const float adv = asad[(size_t)n * 2 + 1];
  const char* fb = (const char*)f;
  const size_t loff = (size_t)lane * 4;
  float a0 = 0.f, a1 = 0.f;

  auto fma2 = [&](uint32_t v, float w) { a0 += w * bflo(v); a1 += w * bfhi(v); };

  if (deg <= 64) {
    const bool valid = lane < deg;
    int s = 0;
    float e = -1e30f;
    if (valid) { s = cs[r0 + lane]; e = lrelu(asad[(size_t)s * 2] + adv); }
    float m = e;
#pragma unroll
    for (int d = 1; d < 64; d <<= 1) m = fmaxf(m, __shfl_xor(m, d));
    float x = valid ? __expf(e - m) : 0.f;
    float den = x;
#pragma unroll
    for (int d = 1; d < 64; d <<= 1) den += __shfl_xor(den, d);
    if (valid) { sb[wv][lane] = s * 256; wl[wv][lane] = x / (den + 1e-16f); }
    __builtin_amdgcn_wave_barrier();
    int g = 0;
    for (; g + 8 <= deg; g += 8) {
      uint32_t b[8];
      float w[8];
#pragma unroll
      for (int k = 0; k < 8; ++k) {
        b[k] = *(const uint32_t*)(fb + (size_t)sb[wv][g + k] + loff);
        w[k] = wl[wv][g + k];
      }
#pragma unroll
      for (int k = 0; k < 8; ++k) { a0 += w[k] * bflo(b[k]); a1 += w[k] * bfhi(b[k]); }
    }
    for (; g < deg; ++g)
      fma2(*(const uint32_t*)(fb + (size_t)sb[wv][g] + loff), wl[wv][g]);
  } else {
    float m = -1e30f;
    for (int i = r0 + lane; i < r1; i += 64) m = fmaxf(m, lrelu(asad[(size_t)cs[i] * 2] + adv));
#pragma unroll
    for (int d = 1; d < 64; d <<= 1) m = fmaxf(m, __shfl_xor(m, d));
    float den = 0.f;
    for (int i = r0 + lane; i < r1; i += 64) den += __expf(lrelu(asad[(size_t)cs[i] * 2] + adv) - m);
#pragma unroll
    for (int d = 1; d < 64; d <<= 1) den += __shfl_xor(den, d);
    const float dinv = 1.f / (den + 1e-16f);
    for (int base = r0; base < r1; base += 64) {
      const int ne = min(64, r1 - base);
      if (lane < ne) {
        const int s = cs[base + lane];
        sb[wv][lane] = s * 256;
        wl[wv][lane] = __expf(lrelu(asad[(size_t)s * 2] + adv) - m) * dinv;
      }
      __builtin_amdgcn_wave_barrier();
      for (int g = 0; g < ne; ++g)
        fma2(*(const uint32_t*)(fb + (size_t)sb[wv][g] + loff), wl[wv][g]);
      __builtin_amdgcn_wave_barrier();
    }
  }
  *(uint32_t*)&agg[(size_t)n * 128 + lane * 2] = pack2bf(a0, a1);
}

// ---------------- fused classifier tail ----------------

__global__ __launch_bounds__(256) void mlp_tail(const bf16_t* __restrict__ A,
                                                const bf16_t* __restrict__ M3t,
                                                const float* __restrict__ bm,
                                                const bf16_t* __restrict__ l2t,
                                                const float* __restrict__ l2b,
                                                const bf16_t* __restrict__ l3t,
                                                const float* __restrict__ l3b,
                                                float* __restrict__ out, int M) {
  __shared__ __align__(16) bf16_t As[128 * 128];
  __shared__ __align__(16) bf16_t Ws[128 * 128];
  const int t = threadIdx.x, wave = t >> 6, lane = t & 63;
  const int ln15 = lane & 15, quad = lane >> 4;
  const int bmr = blockIdx.x * 128;
  const int rowLim = M - 1 - bmr;

#pragma unroll
  for (int r = 0; r < 8; ++r) {
    int base = (wave * 8 + r) * 1024;
    int flat = base + lane * 16;
    int row = flat >> 8;
    int grow = row < rowLim ? row : rowLim;
    const char* gp = (const char*)A + (size_t)grow * 256 + (flat & 255);
    __builtin_amdgcn_global_load_lds((const AS1 void*)gp,
                                     (AS3 void*)((char*)As + base), 16, 0, 0);
  }
#pragma unroll
  for (int r = 0; r < 8; ++r) {
    int base = (wave * 8 + r) * 1024;
    __builtin_amdgcn_global_load_lds((const AS1 void*)((const char*)M3t + base + lane * 16),
                                     (AS3 void*)((char*)Ws + base), 16, 0, 0);
  }
  __syncthreads();

  const int wm = wave * 32;
  f32x4 a1[2][8];
#pragma unroll
  for (int mi = 0; mi < 2; ++mi)
#pragma unroll
    for (int ni = 0; ni < 8; ++ni) a1[mi][ni] = (f32x4){0.f, 0.f, 0.f, 0.f};
#pragma unroll
  for (int kk = 0; kk < 128; kk += 32) {
    bf16x8 af[2];
#pragma unroll
    for (int mi = 0; mi < 2; ++mi)
      af[mi] = *(const bf16x8*)&As[(wm + mi * 16 + ln15) * 128 + kk + quad * 8];
#pragma unroll
    for (int ni = 0; ni < 8; ++ni) {
      bf16x8 bf = *(const bf16x8*)&Ws[(ni * 16 + ln15) * 128 + kk + quad * 8];
#pragma unroll
      for (int mi = 0; mi < 2; ++mi)
        a1[mi][ni] = __builtin_amdgcn_mfma_f32_16x16x32_bf16(af[mi], bf, a1[mi][ni], 0, 0, 0);
    }
  }
  __syncthreads();

#pragma unroll
  for (int r = 0; r < 4; ++r) {
    int base = (wave * 4 + r) * 1024;
    __builtin_amdgcn_global_load_lds((const AS1 void*)((const char*)l2t + base + lane * 16),
                                     (AS3 void*)((char*)Ws + base), 16, 0, 0);
  }
#pragma unroll
  for (int r = 0; r < 2; ++r) {
    int base = (wave * 2 + r) * 1024;
    __builtin_amdgcn_global_load_lds((const AS1 void*)((const char*)l3t + base + lane * 16),
                                     (AS3 void*)((char*)Ws + 8192 * 2 + base), 16, 0, 0);
  }
#pragma unroll
  for (int mi = 0; mi < 2; ++mi) {
    int r0 = wm + mi * 16 + quad * 4;
#pragma unroll
    for (int ni = 0; ni < 8; ++ni) {
      int c = ni * 16 + ln15;
      float bv = bm[c];
#pragma unroll
      for (int reg = 0; reg < 4; ++reg)
        As[(r0 + reg) * 128 + c] = (bf16_t)fmaxf(a1[mi][ni][reg] + bv, 0.f);
    }
  }
  __syncthreads();

  f32x4 a2[2][4];
#pragma unroll
  for (int mi = 0; mi < 2; ++mi)
#pragma unroll
    for (int ni = 0; ni < 4; ++ni) a2[mi][ni] = (f32x4){0.f, 0.f, 0.f, 0.f};
#pragma unroll
  for (int kk = 0; kk < 128; kk += 32) {
    bf16x8 af[2];
#pragma unroll
    for (int mi = 0; mi < 2; ++mi)
      af[mi] = *(const bf16x8*)&As[(wm + mi * 16 + ln15) * 128 + kk + quad * 8];
#pragma unroll
    for (int ni = 0; ni < 4; ++ni) {
      bf16x8 bf = *(const bf16x8*)&Ws[(ni * 16 + ln15) * 128 + kk + quad * 8];
#pragma unroll
      for (int mi = 0; mi < 2; ++mi)
        a2[mi][ni] = __builtin_amdgcn_mfma_f32_16x16x32_bf16(af[mi], bf, a2[mi][ni], 0, 0, 0);
    }
  }
  __syncthreads();

#pragma unroll
  for (int mi = 0; mi < 2; ++mi) {
    int r0 = wm + mi * 16 + quad * 4;
#pragma unroll
    for (int ni = 0; ni < 4; ++ni) {
      int c = ni * 16 + ln15;
      float bv = l2b[c];
#pragma unroll
      for (int reg = 0; reg < 4; ++reg)
        As[(r0 + reg) * 64 + c] = (bf16_t)fmaxf(a2[mi][ni][reg] + bv, 0.f);
    }
  }
  __syncthreads();

  f32x4 a3[2][4];
#pragma unroll
  for (int mi = 0; mi < 2; ++mi)
#pragma unroll
    for (int ni = 0; ni < 4; ++ni) a3[mi][ni] = (f32x4){0.f, 0.f, 0.f, 0.f};
#pragma unroll
  for (int kk = 0; kk < 64; kk += 32) {
    bf16x8 af[2];
#pragma unroll
    for (int mi = 0; mi < 2; ++mi)
      af[mi] = *(const bf16x8*)&As[(wm + mi * 16 + ln15) * 64 + kk + quad * 8];
#pragma unroll
    for (int ni = 0; ni < 4; ++ni) {
      bf16x8 bf = *(const bf16x8*)&Ws[8192 + (ni * 16 + ln15) * 64 + kk + quad * 8];
#pragma unroll
      for (int mi = 0; mi < 2; ++mi)
        a3[mi][ni] = __builtin_amdgcn_mfma_f32_16x16x32_bf16(af[mi], bf, a3[mi][ni], 0, 0, 0);
    }
  }
#pragma unroll
  for (int mi = 0; mi < 2; ++mi) {
    int r0 = wm + mi * 16 + quad * 4;
#pragma unroll
    for (int ni = 0; ni < 4; ++ni) {
      int c = ni * 16 + ln15;
      float bv = l3b[c];
#pragma unroll
      for (int reg = 0; reg < 4; ++reg) {
        int r = bmr + r0 + reg;
        if (r < M) {
          float v = a3[mi][ni][reg] + bv;
          out[(size_t)r * 64 + c] = 1.f / (1.f + __expf(-v));
        }
      }
    }
  }
}

// ---------------- launch ----------------

extern "C" void kernel_launch(void* const* d_in, const int* in_sizes, int n_in,
                              void* d_out, int out_size, void* d_ws, size_t ws_size,
                              hipStream_t stream) {
  const float* x      = (const float*)d_in[0];
  const int*   ei     = (const int*)d_in[1];
  const float* W1     = (const float*)d_in[2];
  const float* a_src1 = (const float*)d_in[3];
  const float* a_dst1 = (const float*)d_in[4];
  const float* b1     = (const float*)d_in[5];
  const float* W2     = (const float*)d_in[6];
  const float* a_src2 = (const float*)d_in[7];
  const float* a_dst2 = (const float*)d_in[8];
  const float* b2     = (const float*)d_in[9];
  const float* W3     = (const float*)d_in[10];
  const float* a_src3 = (const float*)d_in[11];
  const float* a_dst3 = (const float*)d_in[12];
  const float* b3     = (const float*)d_in[13];
  const float* bn1g = (const float*)d_in[14];
  const float* bn1b = (const float*)d_in[15];
  const float* bn1m = (const float*)d_in[16];
  const float* bn1v = (const float*)d_in[17];
  const float* bn2g = (const float*)d_in[18];
  const float* bn2b = (const float*)d_in[19];
  const float* bn2m = (const float*)d_in[20];
  const float* bn2v = (const float*)d_in[21];
  const float* l1w = (const float*)d_in[22];
  const float* l1b = (const float*)d_in[23];
  const float* l2w = (const float*)d_in[24];
  const float* l2b = (const float*)d_in[25];
  const float* l3w = (const float*)d_in[26];
  const float* l3b = (const float*)d_in[27];
  float* out = (float*)d_out;

  const int N = NN;
  const int E = in_sizes[1] / 2;
  const int ET = E + N;
  const int EB = (ET + 255) / 256;

  char* p = (char*)d_ws;
  auto carve = [&](size_t bytes) {
    char* q = p;
    p += (bytes + 255) & ~(size_t)255;
    return q;
  };
  bf16_t* xb    = (bf16_t*)carve((size_t)N * 256 * 2);
  bf16_t* aggb  = (bf16_t*)carve((size_t)N * 1024 * 2);
  bf16_t* f1b   = (bf16_t*)carve((size_t)N * 128 * 2);
  bf16_t* f2b   = (bf16_t*)carve((size_t)N * 128 * 2);
  float* asadA  = (float*)carve((size_t)N * 8 * 4);
  float* asadB  = (float*)carve((size_t)N * 8 * 4);
  float* asadC  = (float*)carve((size_t)N * 2 * 4);
  int* cnt      = (int*)carve((size_t)N * 4);
  int* cursor   = (int*)carve((size_t)N * 4);
  int* row_ptr  = (int*)carve((size_t)(N + 1) * 4);
  int* col      = (int*)carve((size_t)ET * 4);
  bf16_t* Ws1t  = (bf16_t*)carve((size_t)128 * 1024 * 2);
  bf16_t* Ws2t  = (bf16_t*)carve((size_t)128 * 512 * 2);
  bf16_t* M3t   = (bf16_t*)carve((size_t)128 * 128 * 2);
  bf16_t* l2t   = (bf16_t*)carve((size_t)64 * 128 * 2);
  bf16_t* l3t   = (bf16_t*)carve((size_t)64 * 64 * 2);
  float* P1     = (float*)carve((size_t)8 * 256 * 4);
  float* P2     = (float*)carve((size_t)8 * 128 * 4);
  float* P3     = (float*)carve((size_t)2 * 128 * 4);
  float* bm     = (float*)carve((size_t)128 * 4);
  (void)ws_size; (void)n_in; (void)out_size;

  hipMemsetAsync(cnt, 0, (size_t)N * 4, stream);

  Prep1Args pa;
  pa.wp.d[0] = {W1,  Ws1t, 256, 128, 4, 0.25f, 0};
  pa.wp.d[1] = {W2,  Ws2t, 128, 128, 4, 0.25f, 128};
  pa.wp.d[2] = {l2w, l2t,  128, 64,  1, 1.0f,  192};
  pa.wp.d[3] = {l3w, l3t,  64,  64,  1, 1.0f,  200};
  pa.W1 = W1; pa.as1 = a_src1; pa.ad1 = a_dst1;
  pa.W2 = W2; pa.as2 = a_src2; pa.ad2 = a_dst2;
  pa.W3 = W3; pa.as3 = a_src3; pa.ad3 = a_dst3;
  pa.P1 = P1; pa.P2 = P2; pa.P3 = P3;
  pa.W3m = W3; pa.L1w = l1w; pa.b3v = b3; pa.l1b = l1b;
  pa.M3t = M3t; pa.bm = bm;
  pa.ei = ei; pa.E = E; pa.N = N; pa.EB = EB;
  pa.cnt = cnt;
  prep1<<<780 + EB, 256, 0, stream>>>(pa);

  scan_kernel<<<1, 1024, 0, stream>>>(cnt, row_ptr, cursor, N);
  scatter_cast<<<EB + N / 4, 256, 0, stream>>>(ei, E, N, EB, cursor, col, x, P1, xb, asadA);

  const int gm = (N + 127) / 128;  // 157
  const int ab = N / 4;            // 5000
  const int gb = N / 2;            // 10000 gather blocks (2 nodes each)

  // --- GAT layer 1 ---
  gat_agg_in4<256><<<gb, 128, 0, stream>>>(xb, asadA, row_ptr, col, aggb);
  gemm_mfma<64, 3, bf16_t><<<dim3(gm, 2), 256, 0, stream>>>(
      aggb, Ws1t, b1, bn1g, bn1b, bn1m, bn1v, f1b, N, 128, 1024);

  // --- GAT layer 2 ---
  alpha_gemm<128, 4><<<ab, 256, 0, stream>>>(f1b, P2, asadB);
  gat_agg_in4<128><<<gb, 128, 0, stream>>>(f1b, asadB, row_ptr, col, aggb);
  gemm_mfma<64, 3, bf16_t><<<dim3(gm, 2), 256, 0, stream>>>(
      aggb, Ws2t, b2, bn2g, bn2b, bn2m, bn2v, f2b, N, 128, 512);

  // --- GAT layer 3 (H=1) + fused classifier tail ---
  alpha_gemm<128, 1><<<ab, 256, 0, stream>>>(f2b, P3, asadC);
  gat_agg_in1<<<gb, 128, 0, stream>>>(f2b, asadC, row_ptr, col, aggb);
  mlp_tail<<<gm, 256, 0, stream>>>(aggb, M3t, bm, l2t, l2b, l3t, l3b, out, N);
}